// Round 3
// baseline (3232.293 us; speedup 1.0000x reference)
//
#include <hip/hip_runtime.h>

// ---------------------------------------------------------------------------
// DiT graph-attention block, MI355X (gfx950).
// ws layout (~235 MB): modv[M,1536]b | D(76.8MB: cs/qkv/h2|aggb/hbuf2) |
//   denom | bf16^T weights | small. agg + hbuf live inside d_out.
// R2 fix: fill_zero4(denom) was passed a FLOAT count where the kernel takes a
// FLOAT4 count -> zeroed 6.4MB from denom, wiping Wot/W1t/W2t => out == x.
// ---------------------------------------------------------------------------

typedef __attribute__((ext_vector_type(8))) short bf16x8;
typedef __attribute__((ext_vector_type(4))) float f32x4;

__device__ __forceinline__ float bf2f(unsigned short u) {
  union { float f; unsigned int i; } x; x.i = ((unsigned int)u) << 16; return x.f;
}
__device__ __forceinline__ unsigned short f2bf(float f) {
  union { float f; unsigned int i; } x; x.f = f;
  unsigned int r = x.i + 0x7fffu + ((x.i >> 16) & 1u);  // RNE
  return (unsigned short)(r >> 16);
}

__device__ __forceinline__ void gload_lds16(const void* g, void* l) {
  __builtin_amdgcn_global_load_lds(
      (const __attribute__((address_space(1))) void*)g,
      (__attribute__((address_space(3))) void*)l, 16, 0, 0);
}

// ---------------------------------------------------------------------------
// Unified bf16 GEMM:  out = epilogue(A[M,K] @ Bt[N,K]^T + bias)
// EPI 0: out bf16 = acc+bias
// EPI 1: out bf16 = gelu_tanh(acc+bias)
// EPI 2: out f32  = xin + gate*(acc+bias)   (gate bf16, row stride 1536;
//                   xin may alias out: per-thread-unique RMW)
// ---------------------------------------------------------------------------
template <int EPI>
__global__ __launch_bounds__(256)
void gemm_bf16(const unsigned short* __restrict__ A,
               const unsigned short* __restrict__ Bt,
               const float* __restrict__ bias,
               const float* __restrict__ xin,
               const unsigned short* __restrict__ gate,
               void* __restrict__ out,
               int M, int N, int K) {
  __shared__ unsigned short At[128 * 64];
  __shared__ unsigned short Bs[128 * 64];
  const int tid = threadIdx.x;
  const int wid = tid >> 6;
  const int lane = tid & 63;
  const int l15 = lane & 15, l4 = lane >> 4;
  const int row0 = blockIdx.x * 128, col0 = blockIdx.y * 128;
  const int wr = (wid >> 1) * 64, wc = (wid & 1) * 64;

  f32x4 acc[4][4];
  const f32x4 zf = {0.f, 0.f, 0.f, 0.f};
  for (int m = 0; m < 4; ++m)
    for (int n = 0; n < 4; ++n) acc[m][n] = zf;

  for (int kt = 0; kt < K; kt += 64) {
    __syncthreads();
    // stage 128x64 bf16 tiles; LDS dest linear (global_load_lds), swizzle on
    // the global SOURCE column byte: logical = phys ^ ((row&7)<<4)
#pragma unroll
    for (int s = 0; s < 4; ++s) {
      const int p = s * 4096 + tid * 16;           // physical byte in tile
      const int r = p >> 7;                        // tile row
      const int scb = (p & 127) ^ ((r & 7) << 4);  // source column byte
      int gr = row0 + r; gr = gr < M ? gr : M - 1;
      gload_lds16((const char*)A + ((size_t)gr * K + kt) * 2 + scb,
                  (char*)At + s * 4096 + wid * 1024);
      const int gc = col0 + r;                     // N is a multiple of 128
      gload_lds16((const char*)Bt + ((size_t)gc * K + kt) * 2 + scb,
                  (char*)Bs + s * 4096 + wid * 1024);
    }
    __syncthreads();
#pragma unroll
    for (int kk = 0; kk < 64; kk += 32) {
      bf16x8 af[4], bfr[4];
#pragma unroll
      for (int m = 0; m < 4; ++m) {
        const int r = wr + m * 16 + l15;
        const int cb = ((kk + l4 * 8) * 2) ^ ((r & 7) << 4);
        af[m] = *(const bf16x8*)((const char*)At + r * 128 + cb);
      }
#pragma unroll
      for (int n = 0; n < 4; ++n) {
        const int r = wc + n * 16 + l15;
        const int cb = ((kk + l4 * 8) * 2) ^ ((r & 7) << 4);
        bfr[n] = *(const bf16x8*)((const char*)Bs + r * 128 + cb);
      }
#pragma unroll
      for (int m = 0; m < 4; ++m)
#pragma unroll
        for (int n = 0; n < 4; ++n)
          acc[m][n] = __builtin_amdgcn_mfma_f32_16x16x32_bf16(af[m], bfr[n],
                                                              acc[m][n], 0, 0, 0);
    }
  }

  // C/D layout: col=lane&15, row=(lane>>4)*4+reg   [guide §3, m89/m91]
#pragma unroll
  for (int m = 0; m < 4; ++m) {
#pragma unroll
    for (int j = 0; j < 4; ++j) {
      const int gr = row0 + wr + m * 16 + l4 * 4 + j;
      if (gr >= M) continue;
#pragma unroll
      for (int n = 0; n < 4; ++n) {
        const int gc = col0 + wc + n * 16 + l15;
        float v = acc[m][n][j] + bias[gc];
        if (EPI == 0) {
          ((unsigned short*)out)[(size_t)gr * N + gc] = f2bf(v);
        } else if (EPI == 1) {
          float t = tanhf(0.7978845608f * (v + 0.044715f * v * v * v));
          ((unsigned short*)out)[(size_t)gr * N + gc] = f2bf(0.5f * v * (1.f + t));
        } else {
          float gt = bf2f(gate[(size_t)gr * 1536 + gc]);
          ((float*)out)[(size_t)gr * N + gc] = xin[(size_t)gr * N + gc] + gt * v;
        }
      }
    }
  }
}

// ---------------------------------------------------------------------------
// helpers
// ---------------------------------------------------------------------------
// n4 = number of FLOAT4 (16-byte) elements to zero
__global__ void fill_zero4(float* p, long n4) {
  long i = (long)blockIdx.x * blockDim.x + threadIdx.x;
  const long st = (long)gridDim.x * blockDim.x;
  const float4 z = make_float4(0.f, 0.f, 0.f, 0.f);
  for (; i < n4; i += st) ((float4*)p)[i] = z;
}

__global__ void sentinel_fill(float* o, long n, float v) {
  long i = (long)blockIdx.x * blockDim.x + threadIdx.x;
  const long st = (long)gridDim.x * blockDim.x;
  for (; i < n; i += st) o[i] = (i == 0) ? v : 0.f;
}

// Wt[n*kcnt + kk] = bf16(W[(koff+kk)*N + n]),  W logical [Ktot,N] row-major
__global__ void transpose_cast(const float* __restrict__ W,
                               unsigned short* __restrict__ Wt,
                               int N, int koff, int kcnt) {
  int i = blockIdx.x * blockDim.x + threadIdx.x;
  if (i >= kcnt * N) return;
  int kk = i / N, n = i - kk * N;
  Wt[(size_t)n * kcnt + kk] = f2bf(W[(size_t)(koff + kk) * N + n]);
}

__global__ void concat_bias(const float* __restrict__ bq, const float* __restrict__ bk,
                            const float* __restrict__ bv, float* __restrict__ o) {
  int i = blockIdx.x * blockDim.x + threadIdx.x;
  if (i < 256) o[i] = bq[i];
  else if (i < 512) o[i] = bk[i - 256];
  else if (i < 768) o[i] = bv[i - 512];
}

__global__ void silu_cast(const float* __restrict__ c, unsigned short* __restrict__ o,
                          int total4) {
  int i = blockIdx.x * blockDim.x + threadIdx.x;
  if (i >= total4) return;
  float4 v = *(const float4*)&c[(size_t)i * 4];
  ushort4 r;
  r.x = f2bf(v.x / (1.f + expf(-v.x)));
  r.y = f2bf(v.y / (1.f + expf(-v.y)));
  r.z = f2bf(v.z / (1.f + expf(-v.z)));
  r.w = f2bf(v.w / (1.f + expf(-v.w)));
  *(ushort4*)&o[(size_t)i * 4] = r;
}

// one wave per row: h = ((x-mean)*rstd)*(1+scale)+shift -> bf16
__global__ void ln_modulate(const float* __restrict__ xin,
                            const unsigned short* __restrict__ modv,
                            unsigned short* __restrict__ hout,
                            int M, int cshift, int cscale) {
  const int wid = threadIdx.x >> 6, lane = threadIdx.x & 63;
  const int row = blockIdx.x * 4 + wid;
  if (row >= M) return;
  const float4 x4 = *(const float4*)&xin[(size_t)row * 256 + lane * 4];
  float s = x4.x + x4.y + x4.z + x4.w;
  float ss = x4.x * x4.x + x4.y * x4.y + x4.z * x4.z + x4.w * x4.w;
#pragma unroll
  for (int m = 1; m < 64; m <<= 1) {
    s += __shfl_xor(s, m, 64);
    ss += __shfl_xor(ss, m, 64);
  }
  const float mean = s * (1.f / 256.f);
  const float var = ss * (1.f / 256.f) - mean * mean;
  const float rstd = rsqrtf(var + 1e-6f);
  const ushort4 sh4 = *(const ushort4*)&modv[(size_t)row * 1536 + cshift * 256 + lane * 4];
  const ushort4 sc4 = *(const ushort4*)&modv[(size_t)row * 1536 + cscale * 256 + lane * 4];
  ushort4 o;
  o.x = f2bf((x4.x - mean) * rstd * (1.f + bf2f(sc4.x)) + bf2f(sh4.x));
  o.y = f2bf((x4.y - mean) * rstd * (1.f + bf2f(sc4.y)) + bf2f(sh4.y));
  o.z = f2bf((x4.z - mean) * rstd * (1.f + bf2f(sc4.z)) + bf2f(sh4.z));
  o.w = f2bf((x4.w - mean) * rstd * (1.f + bf2f(sc4.w)) + bf2f(sh4.w));
  *(ushort4*)&hout[(size_t)row * 256 + lane * 4] = o;
}

// detect int64 vs int32 edge_index (int64 -> hi dwords of first entries are 0)
__global__ void detect_i64(const unsigned int* __restrict__ e, int E, int* flag) {
  int n = E < 256 ? E : 256;
  int ok = 1;
  for (int i = 0; i < n; ++i)
    if (e[2 * i + 1] != 0u) { ok = 0; break; }
  *flag = ok;
}

// one wave per edge: sim = q[dst].k[src]/sqrt(32) per head (8 heads x 32 dims);
// denom[dst][h] += exp(sim); agg[dst][:] += v[src]*exp(sim)
__global__ void edge_attn(const void* __restrict__ ei, const int* __restrict__ flag,
                          const unsigned short* __restrict__ qkv,
                          float* __restrict__ denom, float* __restrict__ agg, int E) {
  const int wid = threadIdx.x >> 6, lane = threadIdx.x & 63;
  const int e = blockIdx.x * 4 + wid;
  if (e >= E) return;
  int src, dst;
  if (*flag) {
    const long long* p = (const long long*)ei;
    src = (int)p[e]; dst = (int)p[E + e];
  } else {
    const int* p = (const int*)ei;
    src = p[e]; dst = p[E + e];
  }
  const ushort4 q4 = *(const ushort4*)&qkv[(size_t)dst * 768 + lane * 4];
  const ushort4 k4 = *(const ushort4*)&qkv[(size_t)src * 768 + 256 + lane * 4];
  float s = bf2f(q4.x) * bf2f(k4.x) + bf2f(q4.y) * bf2f(k4.y) +
            bf2f(q4.z) * bf2f(k4.z) + bf2f(q4.w) * bf2f(k4.w);
  s += __shfl_xor(s, 1, 64);
  s += __shfl_xor(s, 2, 64);
  s += __shfl_xor(s, 4, 64);  // 8-lane group = one head (32 dims)
  const float ex = expf(s * 0.17677669529663687f);  // 32^-0.5
  if ((lane & 7) == 0) atomicAdd(&denom[(size_t)dst * 8 + (lane >> 3)], ex);
  const ushort4 v4 = *(const ushort4*)&qkv[(size_t)src * 768 + 512 + lane * 4];
  float* ap = &agg[(size_t)dst * 256 + lane * 4];
  atomicAdd(ap + 0, bf2f(v4.x) * ex);
  atomicAdd(ap + 1, bf2f(v4.y) * ex);
  atomicAdd(ap + 2, bf2f(v4.z) * ex);
  atomicAdd(ap + 3, bf2f(v4.w) * ex);
}

__global__ void agg_norm(const float* __restrict__ agg, const float* __restrict__ denom,
                         unsigned short* __restrict__ out, int M) {
  int i = blockIdx.x * blockDim.x + threadIdx.x;  // 4-element groups
  if (i >= M * 64) return;
  int row = i >> 6;
  int c4 = i & 63;
  float d = denom[(size_t)row * 8 + (c4 >> 3)];
  float inv = d > 0.f ? 1.f / d : 0.f;
  float4 a = *(const float4*)&agg[(size_t)row * 256 + c4 * 4];
  ushort4 r;
  r.x = f2bf(a.x * inv); r.y = f2bf(a.y * inv);
  r.z = f2bf(a.z * inv); r.w = f2bf(a.w * inv);
  *(ushort4*)&out[(size_t)row * 256 + c4 * 4] = r;
}

// ---------------------------------------------------------------------------
extern "C" void kernel_launch(void* const* d_in, const int* in_sizes, int n_in,
                              void* d_out, int out_size, void* d_ws, size_t ws_size,
                              hipStream_t stream) {
  (void)n_in;
  const float* x  = (const float*)d_in[0];
  const float* c  = (const float*)d_in[1];
  const void*  ei = d_in[2];
  const float* Wq = (const float*)d_in[3];
  const float* bq = (const float*)d_in[4];
  const float* Wk = (const float*)d_in[5];
  const float* bk = (const float*)d_in[6];
  const float* Wv = (const float*)d_in[7];
  const float* bv = (const float*)d_in[8];
  const float* Wo = (const float*)d_in[9];
  const float* bo = (const float*)d_in[10];
  const float* W1 = (const float*)d_in[11];
  const float* b1 = (const float*)d_in[12];
  const float* W2 = (const float*)d_in[13];
  const float* b2 = (const float*)d_in[14];
  const float* Wc = (const float*)d_in[15];
  const float* bc = (const float*)d_in[16];

  const int M = in_sizes[0] / 256;   // 50000
  const int E = in_sizes[2] / 2;     // 800000

  char* ws = (char*)d_ws;
  size_t off = 0;
  auto carve = [&](size_t bytes) {
    char* p = ws + off;
    off = (off + bytes + 255) & ~(size_t)255;
    return p;
  };
  // persistent
  unsigned short* modv = (unsigned short*)carve((size_t)M * 1536 * 2);  // 153.6MB
  // multi-use region D (76.8MB): cs/qkv/h2-half at +0; aggb/hbuf2 at +51.2MB
  char* D = carve((size_t)M * 768 * 2);
  unsigned short* cs    = (unsigned short*)D;                       // [M,256]b
  unsigned short* qkv   = (unsigned short*)D;                       // [M,768]b
  unsigned short* h2h   = (unsigned short*)D;                       // [M,512]b
  unsigned short* aggb  = (unsigned short*)(D + (size_t)M * 1024);  // [M,256]b
  unsigned short* hbuf2 = (unsigned short*)(D + (size_t)M * 1024);  // [M,256]b
  float* denom = (float*)carve((size_t)M * 32);
  unsigned short* Wct   = (unsigned short*)carve((size_t)1536 * 256 * 2);
  unsigned short* Wqkvt = (unsigned short*)carve((size_t)768 * 256 * 2);
  unsigned short* Wot   = (unsigned short*)carve((size_t)256 * 256 * 2);
  unsigned short* W1t   = (unsigned short*)carve((size_t)1024 * 256 * 2);
  unsigned short* W2tA  = (unsigned short*)carve((size_t)256 * 512 * 2);
  unsigned short* W2tB  = (unsigned short*)carve((size_t)256 * 512 * 2);
  float* bqkv = (float*)carve(768 * 4);
  float* zbias = (float*)carve(256 * 4);
  int* flag = (int*)carve(256);

  // in-d_out aliases
  unsigned short* hbuf = (unsigned short*)d_out;  // [M,256]b, dead before zero
  float* agg = (float*)d_out;                     // [M,256]f32 atomics target
  float* xout = (float*)d_out;

  if (off > ws_size) {
    // ws too small: encode ws_size into d_out[0] so the absmax reveals it
    sentinel_fill<<<2048, 256, 0, stream>>>((float*)d_out, (long)out_size,
                                            (float)ws_size);
    return;
  }

  const int tb = 256;
  detect_i64<<<1, 1, 0, stream>>>((const unsigned int*)ei, E, flag);
  // weight transposes -> bf16 [N,K] row-major
  transpose_cast<<<(256 * 1536 + tb - 1) / tb, tb, 0, stream>>>(Wc, Wct, 1536, 0, 256);
  transpose_cast<<<(256 * 256 + tb - 1) / tb, tb, 0, stream>>>(Wq, Wqkvt, 256, 0, 256);
  transpose_cast<<<(256 * 256 + tb - 1) / tb, tb, 0, stream>>>(Wk, Wqkvt + 256 * 256, 256, 0, 256);
  transpose_cast<<<(256 * 256 + tb - 1) / tb, tb, 0, stream>>>(Wv, Wqkvt + 512 * 256, 256, 0, 256);
  transpose_cast<<<(256 * 256 + tb - 1) / tb, tb, 0, stream>>>(Wo, Wot, 256, 0, 256);
  transpose_cast<<<(256 * 1024 + tb - 1) / tb, tb, 0, stream>>>(W1, W1t, 1024, 0, 256);
  transpose_cast<<<(512 * 256 + tb - 1) / tb, tb, 0, stream>>>(W2, W2tA, 256, 0, 512);
  transpose_cast<<<(512 * 256 + tb - 1) / tb, tb, 0, stream>>>(W2, W2tB, 256, 512, 512);
  concat_bias<<<3, tb, 0, stream>>>(bq, bk, bv, bqkv);
  fill_zero4<<<1, 64, 0, stream>>>(zbias, 64);   // 64 float4 = 256 floats

  const int MT = (M + 127) / 128;
  // cs = bf16(silu(c))
  silu_cast<<<(M * 64 + tb - 1) / tb, tb, 0, stream>>>(c, cs, M * 64);
  // modv = cs @ Wc + bc            [M,1536]
  gemm_bf16<0><<<dim3(MT, 12), 256, 0, stream>>>(cs, Wct, bc, nullptr, nullptr,
                                                 modv, M, 1536, 256);
  // hbuf(d_out) = modulate(ln(x), shift_msa, scale_msa)
  ln_modulate<<<(M + 3) / 4, 256, 0, stream>>>(x, modv, hbuf, M, 0, 1);
  // qkv = hbuf @ [Wq|Wk|Wv] + [bq|bk|bv]   [M,768]  (overwrites cs: dead)
  gemm_bf16<0><<<dim3(MT, 6), 256, 0, stream>>>(hbuf, Wqkvt, bqkv, nullptr, nullptr,
                                                qkv, M, 768, 256);
  // zero agg (d_out, M*64 float4) + denom (M*2 float4), then edge pass
  fill_zero4<<<2048, 256, 0, stream>>>((float*)d_out, (long)M * 64);
  fill_zero4<<<64, 256, 0, stream>>>(denom, (long)M * 2);
  edge_attn<<<(E + 3) / 4, 256, 0, stream>>>(ei, flag, qkv, denom, agg, E);
  // aggb = bf16(agg/denom)
  agg_norm<<<(M * 64 + tb - 1) / tb, tb, 0, stream>>>(agg, denom, aggb, M);
  // x1(d_out) = x + gate_msa * (aggb @ Wo + bo)
  gemm_bf16<2><<<dim3(MT, 2), 256, 0, stream>>>(aggb, Wot, bo, x, modv + 512,
                                                xout, M, 256, 256);
  // hbuf2 = modulate(ln(x1), shift_mlp, scale_mlp)   (overwrites aggb: dead)
  ln_modulate<<<(M + 3) / 4, 256, 0, stream>>>(xout, modv, hbuf2, M, 3, 4);
  // MLP split into two K=512 halves to halve h2 storage:
  // h2a = gelu(hbuf2 @ W1[:, :512] + b1[:512])
  gemm_bf16<1><<<dim3(MT, 4), 256, 0, stream>>>(hbuf2, W1t, b1, nullptr, nullptr,
                                                h2h, M, 512, 256);
  // x1 += gate_mlp * (h2a @ W2[:512, :])          (in-place RMW, zero bias)
  gemm_bf16<2><<<dim3(MT, 2), 256, 0, stream>>>(h2h, W2tA, zbias, xout, modv + 1280,
                                                xout, M, 256, 512);
  // h2b = gelu(hbuf2 @ W1[:, 512:] + b1[512:])
  gemm_bf16<1><<<dim3(MT, 4), 256, 0, stream>>>(hbuf2, W1t + 512 * 256, b1 + 512,
                                                nullptr, nullptr, h2h, M, 512, 256);
  // out = x1 + gate_mlp * (h2b @ W2[512:, :] + b2)
  gemm_bf16<2><<<dim3(MT, 2), 256, 0, stream>>>(h2h, W2tB, b2, xout, modv + 1280,
                                                xout, M, 256, 512);
}

// Round 4
// 773.717 us; speedup vs baseline: 4.1776x; 4.1776x over previous
//
#include <hip/hip_runtime.h>

// ---------------------------------------------------------------------------
// DiT graph-attention block, MI355X (gfx950).
// R4: edge scatter (211M f32 atomics, 2700us = 84% of total) replaced by
//     CSR-by-dst build + register-accumulating gather (wave per dst).
// ---------------------------------------------------------------------------

typedef __attribute__((ext_vector_type(8))) short bf16x8;
typedef __attribute__((ext_vector_type(4))) float f32x4;

__device__ __forceinline__ float bf2f(unsigned short u) {
  union { float f; unsigned int i; } x; x.i = ((unsigned int)u) << 16; return x.f;
}
__device__ __forceinline__ unsigned short f2bf(float f) {
  union { float f; unsigned int i; } x; x.f = f;
  unsigned int r = x.i + 0x7fffu + ((x.i >> 16) & 1u);  // RNE
  return (unsigned short)(r >> 16);
}

__device__ __forceinline__ void gload_lds16(const void* g, void* l) {
  __builtin_amdgcn_global_load_lds(
      (const __attribute__((address_space(1))) void*)g,
      (__attribute__((address_space(3))) void*)l, 16, 0, 0);
}

// ---------------------------------------------------------------------------
// Unified bf16 GEMM:  out = epilogue(A[M,K] @ Bt[N,K]^T + bias)
// EPI 0: out bf16 = acc+bias
// EPI 1: out bf16 = gelu_tanh(acc+bias)
// EPI 2: out f32  = xin + gate*(acc+bias)   (gate bf16, row stride 1536;
//                   xin may alias out: per-thread-unique RMW)
// ---------------------------------------------------------------------------
template <int EPI>
__global__ __launch_bounds__(256)
void gemm_bf16(const unsigned short* __restrict__ A,
               const unsigned short* __restrict__ Bt,
               const float* __restrict__ bias,
               const float* __restrict__ xin,
               const unsigned short* __restrict__ gate,
               void* __restrict__ out,
               int M, int N, int K) {
  __shared__ unsigned short At[128 * 64];
  __shared__ unsigned short Bs[128 * 64];
  const int tid = threadIdx.x;
  const int wid = tid >> 6;
  const int lane = tid & 63;
  const int l15 = lane & 15, l4 = lane >> 4;
  const int row0 = blockIdx.x * 128, col0 = blockIdx.y * 128;
  const int wr = (wid >> 1) * 64, wc = (wid & 1) * 64;

  f32x4 acc[4][4];
  const f32x4 zf = {0.f, 0.f, 0.f, 0.f};
  for (int m = 0; m < 4; ++m)
    for (int n = 0; n < 4; ++n) acc[m][n] = zf;

  for (int kt = 0; kt < K; kt += 64) {
    __syncthreads();
    // stage 128x64 bf16 tiles; LDS dest linear (global_load_lds), swizzle on
    // the global SOURCE column byte: logical = phys ^ ((row&7)<<4)
#pragma unroll
    for (int s = 0; s < 4; ++s) {
      const int p = s * 4096 + tid * 16;           // physical byte in tile
      const int r = p >> 7;                        // tile row
      const int scb = (p & 127) ^ ((r & 7) << 4);  // source column byte
      int gr = row0 + r; gr = gr < M ? gr : M - 1;
      gload_lds16((const char*)A + ((size_t)gr * K + kt) * 2 + scb,
                  (char*)At + s * 4096 + wid * 1024);
      const int gc = col0 + r;                     // N is a multiple of 128
      gload_lds16((const char*)Bt + ((size_t)gc * K + kt) * 2 + scb,
                  (char*)Bs + s * 4096 + wid * 1024);
    }
    __syncthreads();
#pragma unroll
    for (int kk = 0; kk < 64; kk += 32) {
      bf16x8 af[4], bfr[4];
#pragma unroll
      for (int m = 0; m < 4; ++m) {
        const int r = wr + m * 16 + l15;
        const int cb = ((kk + l4 * 8) * 2) ^ ((r & 7) << 4);
        af[m] = *(const bf16x8*)((const char*)At + r * 128 + cb);
      }
#pragma unroll
      for (int n = 0; n < 4; ++n) {
        const int r = wc + n * 16 + l15;
        const int cb = ((kk + l4 * 8) * 2) ^ ((r & 7) << 4);
        bfr[n] = *(const bf16x8*)((const char*)Bs + r * 128 + cb);
      }
#pragma unroll
      for (int m = 0; m < 4; ++m)
#pragma unroll
        for (int n = 0; n < 4; ++n)
          acc[m][n] = __builtin_amdgcn_mfma_f32_16x16x32_bf16(af[m], bfr[n],
                                                              acc[m][n], 0, 0, 0);
    }
  }

  // C/D layout: col=lane&15, row=(lane>>4)*4+reg   [guide §3, m89/m91]
#pragma unroll
  for (int m = 0; m < 4; ++m) {
#pragma unroll
    for (int j = 0; j < 4; ++j) {
      const int gr = row0 + wr + m * 16 + l4 * 4 + j;
      if (gr >= M) continue;
#pragma unroll
      for (int n = 0; n < 4; ++n) {
        const int gc = col0 + wc + n * 16 + l15;
        float v = acc[m][n][j] + bias[gc];
        if (EPI == 0) {
          ((unsigned short*)out)[(size_t)gr * N + gc] = f2bf(v);
        } else if (EPI == 1) {
          float t = tanhf(0.7978845608f * (v + 0.044715f * v * v * v));
          ((unsigned short*)out)[(size_t)gr * N + gc] = f2bf(0.5f * v * (1.f + t));
        } else {
          float gt = bf2f(gate[(size_t)gr * 1536 + gc]);
          ((float*)out)[(size_t)gr * N + gc] = xin[(size_t)gr * N + gc] + gt * v;
        }
      }
    }
  }
}

// ---------------------------------------------------------------------------
// helpers
// ---------------------------------------------------------------------------
// n4 = number of FLOAT4 (16-byte) elements to zero
__global__ void fill_zero4(float* p, long n4) {
  long i = (long)blockIdx.x * blockDim.x + threadIdx.x;
  const long st = (long)gridDim.x * blockDim.x;
  const float4 z = make_float4(0.f, 0.f, 0.f, 0.f);
  for (; i < n4; i += st) ((float4*)p)[i] = z;
}

__global__ void sentinel_fill(float* o, long n, float v) {
  long i = (long)blockIdx.x * blockDim.x + threadIdx.x;
  const long st = (long)gridDim.x * blockDim.x;
  for (; i < n; i += st) o[i] = (i == 0) ? v : 0.f;
}

// Wt[n*kcnt + kk] = bf16(W[(koff+kk)*N + n]),  W logical [Ktot,N] row-major
__global__ void transpose_cast(const float* __restrict__ W,
                               unsigned short* __restrict__ Wt,
                               int N, int koff, int kcnt) {
  int i = blockIdx.x * blockDim.x + threadIdx.x;
  if (i >= kcnt * N) return;
  int kk = i / N, n = i - kk * N;
  Wt[(size_t)n * kcnt + kk] = f2bf(W[(size_t)(koff + kk) * N + n]);
}

__global__ void concat_bias(const float* __restrict__ bq, const float* __restrict__ bk,
                            const float* __restrict__ bv, float* __restrict__ o) {
  int i = blockIdx.x * blockDim.x + threadIdx.x;
  if (i < 256) o[i] = bq[i];
  else if (i < 512) o[i] = bk[i - 256];
  else if (i < 768) o[i] = bv[i - 512];
}

__global__ void silu_cast(const float* __restrict__ c, unsigned short* __restrict__ o,
                          int total4) {
  int i = blockIdx.x * blockDim.x + threadIdx.x;
  if (i >= total4) return;
  float4 v = *(const float4*)&c[(size_t)i * 4];
  ushort4 r;
  r.x = f2bf(v.x / (1.f + expf(-v.x)));
  r.y = f2bf(v.y / (1.f + expf(-v.y)));
  r.z = f2bf(v.z / (1.f + expf(-v.z)));
  r.w = f2bf(v.w / (1.f + expf(-v.w)));
  *(ushort4*)&o[(size_t)i * 4] = r;
}

// one wave per row: h = ((x-mean)*rstd)*(1+scale)+shift -> bf16
__global__ void ln_modulate(const float* __restrict__ xin,
                            const unsigned short* __restrict__ modv,
                            unsigned short* __restrict__ hout,
                            int M, int cshift, int cscale) {
  const int wid = threadIdx.x >> 6, lane = threadIdx.x & 63;
  const int row = blockIdx.x * 4 + wid;
  if (row >= M) return;
  const float4 x4 = *(const float4*)&xin[(size_t)row * 256 + lane * 4];
  float s = x4.x + x4.y + x4.z + x4.w;
  float ss = x4.x * x4.x + x4.y * x4.y + x4.z * x4.z + x4.w * x4.w;
#pragma unroll
  for (int m = 1; m < 64; m <<= 1) {
    s += __shfl_xor(s, m, 64);
    ss += __shfl_xor(ss, m, 64);
  }
  const float mean = s * (1.f / 256.f);
  const float var = ss * (1.f / 256.f) - mean * mean;
  const float rstd = rsqrtf(var + 1e-6f);
  const ushort4 sh4 = *(const ushort4*)&modv[(size_t)row * 1536 + cshift * 256 + lane * 4];
  const ushort4 sc4 = *(const ushort4*)&modv[(size_t)row * 1536 + cscale * 256 + lane * 4];
  ushort4 o;
  o.x = f2bf((x4.x - mean) * rstd * (1.f + bf2f(sc4.x)) + bf2f(sh4.x));
  o.y = f2bf((x4.y - mean) * rstd * (1.f + bf2f(sc4.y)) + bf2f(sh4.y));
  o.z = f2bf((x4.z - mean) * rstd * (1.f + bf2f(sc4.z)) + bf2f(sh4.z));
  o.w = f2bf((x4.w - mean) * rstd * (1.f + bf2f(sc4.w)) + bf2f(sh4.w));
  *(ushort4*)&hout[(size_t)row * 256 + lane * 4] = o;
}

// detect int64 vs int32 edge_index (int64 -> hi dwords of first entries are 0)
__global__ void detect_i64(const unsigned int* __restrict__ e, int E, int* flag) {
  int n = E < 256 ? E : 256;
  int ok = 1;
  for (int i = 0; i < n; ++i)
    if (e[2 * i + 1] != 0u) { ok = 0; break; }
  *flag = ok;
}

// unpack edge_index (int64 or int32) -> src32[E], dst32[E]
__global__ void conv_edges(const void* __restrict__ ei, const int* __restrict__ flag,
                           int* __restrict__ src32, int* __restrict__ dst32, int E) {
  int e = blockIdx.x * blockDim.x + threadIdx.x;
  if (e >= E) return;
  if (*flag) {
    const long long* p = (const long long*)ei;
    src32[e] = (int)p[e]; dst32[e] = (int)p[E + e];
  } else {
    const int* p = (const int*)ei;
    src32[e] = p[e]; dst32[e] = p[E + e];
  }
}

__global__ void hist_deg(const int* __restrict__ dst32, int* __restrict__ deg, int E) {
  int e = blockIdx.x * blockDim.x + threadIdx.x;
  if (e >= E) return;
  atomicAdd(&deg[dst32[e]], 1);
}

// single-block exclusive scan of deg[M] -> start[M+1]; cursor = copy of start
__global__ __launch_bounds__(1024)
void scan_excl(const int* __restrict__ deg, int* __restrict__ start,
               int* __restrict__ cursor, int M) {
  __shared__ int carry;
  __shared__ int wsum[16];
  const int lane = threadIdx.x & 63, w = threadIdx.x >> 6;
  if (threadIdx.x == 0) carry = 0;
  __syncthreads();
  for (int base = 0; base < M; base += 1024) {
    const int i = base + threadIdx.x;
    const int v = (i < M) ? deg[i] : 0;
    int s = v;  // inclusive scan within wave
#pragma unroll
    for (int d = 1; d < 64; d <<= 1) {
      int t = __shfl_up(s, d, 64);
      if (lane >= d) s += t;
    }
    if (lane == 63) wsum[w] = s;
    __syncthreads();
    if (threadIdx.x < 16) {  // inclusive scan of 16 wave sums (wave 0)
      int t = wsum[threadIdx.x];
#pragma unroll
      for (int d = 1; d < 16; d <<= 1) {
        int u = __shfl_up(t, d, 64);
        if (lane >= d) t += u;
      }
      wsum[threadIdx.x] = t;
    }
    __syncthreads();
    const int woff = (w == 0) ? 0 : wsum[w - 1];
    const int incl = s + woff + carry;
    if (i < M) { start[i] = incl - v; cursor[i] = incl - v; }
    __syncthreads();
    if (threadIdx.x == 1023) carry = incl;
    __syncthreads();
  }
  if (threadIdx.x == 0) start[M] = carry;
}

__global__ void csr_fill(const int* __restrict__ src32, const int* __restrict__ dst32,
                         int* __restrict__ cursor, int* __restrict__ csr, int E) {
  int e = blockIdx.x * blockDim.x + threadIdx.x;
  if (e >= E) return;
  int pos = atomicAdd(&cursor[dst32[e]], 1);
  csr[pos] = src32[e];
}

// one wave per dst node: softmax-weighted gather over its in-edges.
// lane holds dims 4l..4l+3; head h = lane>>3 (8 lanes x 4 dims = 32 = HEAD_DIM)
__global__ __launch_bounds__(256)
void attn_gather(const int* __restrict__ csr, const int* __restrict__ start,
                 const unsigned short* __restrict__ qkv,
                 unsigned short* __restrict__ aggb, int M) {
  const int wid = threadIdx.x >> 6, lane = threadIdx.x & 63;
  const int row = blockIdx.x * 4 + wid;
  if (row >= M) return;
  const ushort4 q4 = *(const ushort4*)&qkv[(size_t)row * 768 + lane * 4];
  const float SC = 0.17677669529663687f;  // 32^-0.5, folded into q
  const float qf0 = bf2f(q4.x) * SC, qf1 = bf2f(q4.y) * SC;
  const float qf2 = bf2f(q4.z) * SC, qf3 = bf2f(q4.w) * SC;
  const int b = start[row], e = start[row + 1];
  float den = 0.f, a0 = 0.f, a1 = 0.f, a2 = 0.f, a3 = 0.f;
#pragma unroll 2
  for (int i = b; i < e; ++i) {
    const int src = csr[i];
    const ushort4 k4 = *(const ushort4*)&qkv[(size_t)src * 768 + 256 + lane * 4];
    const ushort4 v4 = *(const ushort4*)&qkv[(size_t)src * 768 + 512 + lane * 4];
    float s = qf0 * bf2f(k4.x) + qf1 * bf2f(k4.y) +
              qf2 * bf2f(k4.z) + qf3 * bf2f(k4.w);
    s += __shfl_xor(s, 1, 64);
    s += __shfl_xor(s, 2, 64);
    s += __shfl_xor(s, 4, 64);
    const float ex = expf(s);
    den += ex;
    a0 += ex * bf2f(v4.x); a1 += ex * bf2f(v4.y);
    a2 += ex * bf2f(v4.z); a3 += ex * bf2f(v4.w);
  }
  const float inv = den > 0.f ? 1.f / den : 0.f;
  ushort4 r;
  r.x = f2bf(a0 * inv); r.y = f2bf(a1 * inv);
  r.z = f2bf(a2 * inv); r.w = f2bf(a3 * inv);
  *(ushort4*)&aggb[(size_t)row * 256 + lane * 4] = r;
}

// ---------------------------------------------------------------------------
extern "C" void kernel_launch(void* const* d_in, const int* in_sizes, int n_in,
                              void* d_out, int out_size, void* d_ws, size_t ws_size,
                              hipStream_t stream) {
  (void)n_in;
  const float* x  = (const float*)d_in[0];
  const float* c  = (const float*)d_in[1];
  const void*  ei = d_in[2];
  const float* Wq = (const float*)d_in[3];
  const float* bq = (const float*)d_in[4];
  const float* Wk = (const float*)d_in[5];
  const float* bk = (const float*)d_in[6];
  const float* Wv = (const float*)d_in[7];
  const float* bv = (const float*)d_in[8];
  const float* Wo = (const float*)d_in[9];
  const float* bo = (const float*)d_in[10];
  const float* W1 = (const float*)d_in[11];
  const float* b1 = (const float*)d_in[12];
  const float* W2 = (const float*)d_in[13];
  const float* b2 = (const float*)d_in[14];
  const float* Wc = (const float*)d_in[15];
  const float* bc = (const float*)d_in[16];

  const int M = in_sizes[0] / 256;   // 50000
  const int E = in_sizes[2] / 2;     // 800000

  char* ws = (char*)d_ws;
  size_t off = 0;
  auto carve = [&](size_t bytes) {
    char* p = ws + off;
    off = (off + bytes + 255) & ~(size_t)255;
    return p;
  };
  // persistent
  unsigned short* modv = (unsigned short*)carve((size_t)M * 1536 * 2);  // 153.6MB
  // multi-use region D (76.8MB): cs/qkv/h2-half at +0; aggb/hbuf2 at +51.2MB
  char* D = carve((size_t)M * 768 * 2);
  unsigned short* cs    = (unsigned short*)D;                       // [M,256]b
  unsigned short* qkv   = (unsigned short*)D;                       // [M,768]b
  unsigned short* h2h   = (unsigned short*)D;                       // [M,512]b
  unsigned short* aggb  = (unsigned short*)(D + (size_t)M * 1024);  // [M,256]b
  unsigned short* hbuf2 = (unsigned short*)(D + (size_t)M * 1024);  // [M,256]b
  unsigned short* Wct   = (unsigned short*)carve((size_t)1536 * 256 * 2);
  unsigned short* Wqkvt = (unsigned short*)carve((size_t)768 * 256 * 2);
  unsigned short* Wot   = (unsigned short*)carve((size_t)256 * 256 * 2);
  unsigned short* W1t   = (unsigned short*)carve((size_t)1024 * 256 * 2);
  unsigned short* W2tA  = (unsigned short*)carve((size_t)256 * 512 * 2);
  unsigned short* W2tB  = (unsigned short*)carve((size_t)256 * 512 * 2);
  float* bqkv = (float*)carve(768 * 4);
  float* zbias = (float*)carve(256 * 4);
  int* flag = (int*)carve(256);
  // CSR buffers
  int* src32  = (int*)carve((size_t)E * 4);
  int* dst32  = (int*)carve((size_t)E * 4);
  int* deg    = (int*)carve((size_t)(M + 4) * 4);
  int* startp = (int*)carve((size_t)(M + 4) * 4);
  int* cursor = (int*)carve((size_t)(M + 4) * 4);
  int* csr    = (int*)carve((size_t)E * 4);

  // in-d_out aliases
  unsigned short* hbuf = (unsigned short*)d_out;  // [M,256]b, dead before Wo
  float* xout = (float*)d_out;

  if (off > ws_size) {
    // ws too small: encode ws_size into d_out[0] so the absmax reveals it
    sentinel_fill<<<2048, 256, 0, stream>>>((float*)d_out, (long)out_size,
                                            (float)ws_size);
    return;
  }

  const int tb = 256;
  const int EB = (E + tb - 1) / tb;
  detect_i64<<<1, 1, 0, stream>>>((const unsigned int*)ei, E, flag);
  // --- CSR build (independent of GEMM chain, same stream) ---
  conv_edges<<<EB, tb, 0, stream>>>(ei, flag, src32, dst32, E);
  fill_zero4<<<64, 256, 0, stream>>>((float*)deg, (long)(M + 4) / 4);
  hist_deg<<<EB, tb, 0, stream>>>(dst32, deg, E);
  scan_excl<<<1, 1024, 0, stream>>>(deg, startp, cursor, M);
  csr_fill<<<EB, tb, 0, stream>>>(src32, dst32, cursor, csr, E);

  // weight transposes -> bf16 [N,K] row-major
  transpose_cast<<<(256 * 1536 + tb - 1) / tb, tb, 0, stream>>>(Wc, Wct, 1536, 0, 256);
  transpose_cast<<<(256 * 256 + tb - 1) / tb, tb, 0, stream>>>(Wq, Wqkvt, 256, 0, 256);
  transpose_cast<<<(256 * 256 + tb - 1) / tb, tb, 0, stream>>>(Wk, Wqkvt + 256 * 256, 256, 0, 256);
  transpose_cast<<<(256 * 256 + tb - 1) / tb, tb, 0, stream>>>(Wv, Wqkvt + 512 * 256, 256, 0, 256);
  transpose_cast<<<(256 * 256 + tb - 1) / tb, tb, 0, stream>>>(Wo, Wot, 256, 0, 256);
  transpose_cast<<<(256 * 1024 + tb - 1) / tb, tb, 0, stream>>>(W1, W1t, 1024, 0, 256);
  transpose_cast<<<(512 * 256 + tb - 1) / tb, tb, 0, stream>>>(W2, W2tA, 256, 0, 512);
  transpose_cast<<<(512 * 256 + tb - 1) / tb, tb, 0, stream>>>(W2, W2tB, 256, 512, 512);
  concat_bias<<<3, tb, 0, stream>>>(bq, bk, bv, bqkv);
  fill_zero4<<<1, 64, 0, stream>>>(zbias, 64);   // 64 float4 = 256 floats

  const int MT = (M + 127) / 128;
  // cs = bf16(silu(c))
  silu_cast<<<(M * 64 + tb - 1) / tb, tb, 0, stream>>>(c, cs, M * 64);
  // modv = cs @ Wc + bc            [M,1536]
  gemm_bf16<0><<<dim3(MT, 12), 256, 0, stream>>>(cs, Wct, bc, nullptr, nullptr,
                                                 modv, M, 1536, 256);
  // hbuf(d_out) = modulate(ln(x), shift_msa, scale_msa)
  ln_modulate<<<(M + 3) / 4, 256, 0, stream>>>(x, modv, hbuf, M, 0, 1);
  // qkv = hbuf @ [Wq|Wk|Wv] + [bq|bk|bv]   [M,768]  (overwrites cs: dead)
  gemm_bf16<0><<<dim3(MT, 6), 256, 0, stream>>>(hbuf, Wqkvt, bqkv, nullptr, nullptr,
                                                qkv, M, 768, 256);
  // aggb = softmax-weighted gather per dst (registers; no atomics)
  attn_gather<<<(M + 3) / 4, 256, 0, stream>>>(csr, startp, qkv, aggb, M);
  // x1(d_out) = x + gate_msa * (aggb @ Wo + bo)
  gemm_bf16<2><<<dim3(MT, 2), 256, 0, stream>>>(aggb, Wot, bo, x, modv + 512,
                                                xout, M, 256, 256);
  // hbuf2 = modulate(ln(x1), shift_mlp, scale_mlp)   (overwrites aggb: dead)
  ln_modulate<<<(M + 3) / 4, 256, 0, stream>>>(xout, modv, hbuf2, M, 3, 4);
  // MLP split into two K=512 halves to halve h2 storage:
  // h2a = gelu(hbuf2 @ W1[:, :512] + b1[:512])
  gemm_bf16<1><<<dim3(MT, 4), 256, 0, stream>>>(hbuf2, W1t, b1, nullptr, nullptr,
                                                h2h, M, 512, 256);
  // x1 += gate_mlp * (h2a @ W2[:512, :])          (in-place RMW, zero bias)
  gemm_bf16<2><<<dim3(MT, 2), 256, 0, stream>>>(h2h, W2tA, zbias, xout, modv + 1280,
                                                xout, M, 256, 512);
  // h2b = gelu(hbuf2 @ W1[:, 512:] + b1[512:])
  gemm_bf16<1><<<dim3(MT, 4), 256, 0, stream>>>(hbuf2, W1t + 512 * 256, b1 + 512,
                                                nullptr, nullptr, h2h, M, 512, 256);
  // out = x1 + gate_mlp * (h2b @ W2[512:, :] + b2)
  gemm_bf16<2><<<dim3(MT, 2), 256, 0, stream>>>(h2h, W2tB, b2, xout, modv + 1280,
                                                xout, M, 256, 512);
}

// Round 5
// 680.752 us; speedup vs baseline: 4.7481x; 1.1366x over previous
//
#include <hip/hip_runtime.h>

// ---------------------------------------------------------------------------
// DiT graph-attention block, MI355X (gfx950).
// R5: XCD-grouped GEMM block mapping (col-siblings share one XCD's L2),
//     kv-interleaved qkv layout (1x16B gather/edge instead of 2x8B),
//     parallel detect + fused conv/hist + 3-phase CSR scan.
// ---------------------------------------------------------------------------

typedef __attribute__((ext_vector_type(8))) short bf16x8;
typedef __attribute__((ext_vector_type(8))) unsigned short u16x8;
typedef __attribute__((ext_vector_type(4))) float f32x4;

__device__ __forceinline__ float bf2f(unsigned short u) {
  union { float f; unsigned int i; } x; x.i = ((unsigned int)u) << 16; return x.f;
}
__device__ __forceinline__ unsigned short f2bf(float f) {
  union { float f; unsigned int i; } x; x.f = f;
  unsigned int r = x.i + 0x7fffu + ((x.i >> 16) & 1u);  // RNE
  return (unsigned short)(r >> 16);
}

__device__ __forceinline__ void gload_lds16(const void* g, void* l) {
  __builtin_amdgcn_global_load_lds(
      (const __attribute__((address_space(1))) void*)g,
      (__attribute__((address_space(3))) void*)l, 16, 0, 0);
}

// ---------------------------------------------------------------------------
// Unified bf16 GEMM:  out = epilogue(A[M,K] @ Bt[N,K]^T + bias)
// 1-D grid with XCD grouping: pid%8 = XCD; within an XCD, col-blocks of one
// row-block are consecutive -> A-tile reused from that XCD's L2.
// EPI 0: out bf16 = acc+bias
// EPI 1: out bf16 = gelu_tanh(acc+bias)
// EPI 2: out f32  = xin + gate*(acc+bias)   (gate bf16, row stride 1536;
//                   xin may alias out: per-thread-unique RMW)
// ---------------------------------------------------------------------------
template <int EPI>
__global__ __launch_bounds__(256)
void gemm_bf16(const unsigned short* __restrict__ A,
               const unsigned short* __restrict__ Bt,
               const float* __restrict__ bias,
               const float* __restrict__ xin,
               const unsigned short* __restrict__ gate,
               void* __restrict__ out,
               int M, int N, int K) {
  const int NT = N >> 7;
  const int MT = (M + 127) >> 7;
  const int pid = blockIdx.x;
  const int xcd = pid & 7;
  const int j = pid >> 3;
  const int rb = xcd + 8 * (j / NT);
  const int cb = j - (j / NT) * NT;
  if (rb >= MT) return;  // uniform across block: no barrier divergence

  __shared__ unsigned short At[128 * 64];
  __shared__ unsigned short Bs[128 * 64];
  const int tid = threadIdx.x;
  const int wid = tid >> 6;
  const int lane = tid & 63;
  const int l15 = lane & 15, l4 = lane >> 4;
  const int row0 = rb * 128, col0 = cb * 128;
  const int wr = (wid >> 1) * 64, wc = (wid & 1) * 64;

  f32x4 acc[4][4];
  const f32x4 zf = {0.f, 0.f, 0.f, 0.f};
  for (int m = 0; m < 4; ++m)
    for (int n = 0; n < 4; ++n) acc[m][n] = zf;

  for (int kt = 0; kt < K; kt += 64) {
    __syncthreads();
    // stage 128x64 bf16 tiles; LDS dest linear (global_load_lds), swizzle on
    // the global SOURCE column byte: logical = phys ^ ((row&7)<<4)
#pragma unroll
    for (int s = 0; s < 4; ++s) {
      const int p = s * 4096 + tid * 16;           // physical byte in tile
      const int r = p >> 7;                        // tile row
      const int scb = (p & 127) ^ ((r & 7) << 4);  // source column byte
      int gr = row0 + r; gr = gr < M ? gr : M - 1;
      gload_lds16((const char*)A + ((size_t)gr * K + kt) * 2 + scb,
                  (char*)At + s * 4096 + wid * 1024);
      const int gc = col0 + r;                     // N is a multiple of 128
      gload_lds16((const char*)Bt + ((size_t)gc * K + kt) * 2 + scb,
                  (char*)Bs + s * 4096 + wid * 1024);
    }
    __syncthreads();
#pragma unroll
    for (int kk = 0; kk < 64; kk += 32) {
      bf16x8 af[4], bfr[4];
#pragma unroll
      for (int m = 0; m < 4; ++m) {
        const int r = wr + m * 16 + l15;
        const int cb2 = ((kk + l4 * 8) * 2) ^ ((r & 7) << 4);
        af[m] = *(const bf16x8*)((const char*)At + r * 128 + cb2);
      }
#pragma unroll
      for (int n = 0; n < 4; ++n) {
        const int r = wc + n * 16 + l15;
        const int cb2 = ((kk + l4 * 8) * 2) ^ ((r & 7) << 4);
        bfr[n] = *(const bf16x8*)((const char*)Bs + r * 128 + cb2);
      }
#pragma unroll
      for (int m = 0; m < 4; ++m)
#pragma unroll
        for (int n = 0; n < 4; ++n)
          acc[m][n] = __builtin_amdgcn_mfma_f32_16x16x32_bf16(af[m], bfr[n],
                                                              acc[m][n], 0, 0, 0);
    }
  }

  // C/D layout: col=lane&15, row=(lane>>4)*4+reg   [guide §3, m89/m91]
#pragma unroll
  for (int m = 0; m < 4; ++m) {
#pragma unroll
    for (int j2 = 0; j2 < 4; ++j2) {
      const int gr = row0 + wr + m * 16 + l4 * 4 + j2;
      if (gr >= M) continue;
#pragma unroll
      for (int n = 0; n < 4; ++n) {
        const int gc = col0 + wc + n * 16 + l15;
        float v = acc[m][n][j2] + bias[gc];
        if (EPI == 0) {
          ((unsigned short*)out)[(size_t)gr * N + gc] = f2bf(v);
        } else if (EPI == 1) {
          float t = tanhf(0.7978845608f * (v + 0.044715f * v * v * v));
          ((unsigned short*)out)[(size_t)gr * N + gc] = f2bf(0.5f * v * (1.f + t));
        } else {
          float gt = bf2f(gate[(size_t)gr * 1536 + gc]);
          ((float*)out)[(size_t)gr * N + gc] = xin[(size_t)gr * N + gc] + gt * v;
        }
      }
    }
  }
}

// ---------------------------------------------------------------------------
// helpers
// ---------------------------------------------------------------------------
// n4 = number of FLOAT4 (16-byte) elements to zero
__global__ void fill_zero4(float* p, long n4) {
  long i = (long)blockIdx.x * blockDim.x + threadIdx.x;
  const long st = (long)gridDim.x * blockDim.x;
  const float4 z = make_float4(0.f, 0.f, 0.f, 0.f);
  for (; i < n4; i += st) ((float4*)p)[i] = z;
}

__global__ void sentinel_fill(float* o, long n, float v) {
  long i = (long)blockIdx.x * blockDim.x + threadIdx.x;
  const long st = (long)gridDim.x * blockDim.x;
  for (; i < n; i += st) o[i] = (i == 0) ? v : 0.f;
}

// Wt[map(n)*kcnt + kk] = bf16(W[(koff+kk)*N + n]);  W logical [Ktot,N] row-major
// mode 0: map(n)=n   mode 1 (k-half of kv-pack): (n/4)*8+(n%4)
// mode 2 (v-half): (n/4)*8+4+(n%4)
__global__ void transpose_cast(const float* __restrict__ W,
                               unsigned short* __restrict__ Wt,
                               int N, int koff, int kcnt, int mode) {
  int i = blockIdx.x * blockDim.x + threadIdx.x;
  if (i >= kcnt * N) return;
  int kk = i / N, n = i - kk * N;
  int r = n;
  if (mode == 1) r = ((n >> 2) << 3) + (n & 3);
  else if (mode == 2) r = ((n >> 2) << 3) + 4 + (n & 3);
  Wt[(size_t)r * kcnt + kk] = f2bf(W[(size_t)(koff + kk) * N + n]);
}

// bias concat with the same kv interleave
__global__ void concat_bias(const float* __restrict__ bq, const float* __restrict__ bk,
                            const float* __restrict__ bv, float* __restrict__ o) {
  int i = blockIdx.x * blockDim.x + threadIdx.x;
  if (i < 256) o[i] = bq[i];
  else if (i < 512) { int d = i - 256; o[256 + ((d >> 2) << 3) + (d & 3)] = bk[d]; }
  else if (i < 768) { int d = i - 512; o[256 + ((d >> 2) << 3) + 4 + (d & 3)] = bv[d]; }
}

__global__ void silu_cast(const float* __restrict__ c, unsigned short* __restrict__ o,
                          int total4) {
  int i = blockIdx.x * blockDim.x + threadIdx.x;
  if (i >= total4) return;
  float4 v = *(const float4*)&c[(size_t)i * 4];
  ushort4 r;
  r.x = f2bf(v.x / (1.f + expf(-v.x)));
  r.y = f2bf(v.y / (1.f + expf(-v.y)));
  r.z = f2bf(v.z / (1.f + expf(-v.z)));
  r.w = f2bf(v.w / (1.f + expf(-v.w)));
  *(ushort4*)&o[(size_t)i * 4] = r;
}

// one wave per row: h = ((x-mean)*rstd)*(1+scale)+shift -> bf16
__global__ void ln_modulate(const float* __restrict__ xin,
                            const unsigned short* __restrict__ modv,
                            unsigned short* __restrict__ hout,
                            int M, int cshift, int cscale) {
  const int wid = threadIdx.x >> 6, lane = threadIdx.x & 63;
  const int row = blockIdx.x * 4 + wid;
  if (row >= M) return;
  const float4 x4 = *(const float4*)&xin[(size_t)row * 256 + lane * 4];
  float s = x4.x + x4.y + x4.z + x4.w;
  float ss = x4.x * x4.x + x4.y * x4.y + x4.z * x4.z + x4.w * x4.w;
#pragma unroll
  for (int m = 1; m < 64; m <<= 1) {
    s += __shfl_xor(s, m, 64);
    ss += __shfl_xor(ss, m, 64);
  }
  const float mean = s * (1.f / 256.f);
  const float var = ss * (1.f / 256.f) - mean * mean;
  const float rstd = rsqrtf(var + 1e-6f);
  const ushort4 sh4 = *(const ushort4*)&modv[(size_t)row * 1536 + cshift * 256 + lane * 4];
  const ushort4 sc4 = *(const ushort4*)&modv[(size_t)row * 1536 + cscale * 256 + lane * 4];
  ushort4 o;
  o.x = f2bf((x4.x - mean) * rstd * (1.f + bf2f(sc4.x)) + bf2f(sh4.x));
  o.y = f2bf((x4.y - mean) * rstd * (1.f + bf2f(sc4.y)) + bf2f(sh4.y));
  o.z = f2bf((x4.z - mean) * rstd * (1.f + bf2f(sc4.z)) + bf2f(sh4.z));
  o.w = f2bf((x4.w - mean) * rstd * (1.f + bf2f(sc4.w)) + bf2f(sh4.w));
  *(ushort4*)&hout[(size_t)row * 256 + lane * 4] = o;
}

// detect int64 vs int32 edge_index (int64 -> hi dwords of first entries are 0)
__global__ void detect_i64(const unsigned int* __restrict__ e, int E, int* flag) {
  __shared__ int bad;
  if (threadIdx.x == 0) bad = 0;
  __syncthreads();
  const int n = E < 256 ? E : 256;
  if ((int)threadIdx.x < n && e[2 * threadIdx.x + 1] != 0u) atomicAdd(&bad, 1);
  __syncthreads();
  if (threadIdx.x == 0) *flag = (bad == 0);
}

// unpack edge_index -> src32/dst32 and histogram dst degree (fused)
__global__ void conv_hist(const void* __restrict__ ei, const int* __restrict__ flag,
                          int* __restrict__ src32, int* __restrict__ dst32,
                          int* __restrict__ deg, int E) {
  int e = blockIdx.x * blockDim.x + threadIdx.x;
  if (e >= E) return;
  int s, d;
  if (*flag) {
    const long long* p = (const long long*)ei;
    s = (int)p[e]; d = (int)p[E + e];
  } else {
    const int* p = (const int*)ei;
    s = p[e]; d = p[E + e];
  }
  src32[e] = s; dst32[e] = d;
  atomicAdd(&deg[d], 1);
}

// 3-phase scan: block sums -> scan of block sums -> per-block scan + offset
__global__ __launch_bounds__(256)
void block_sum(const int* __restrict__ deg, int* __restrict__ bsum, int M) {
  int i = blockIdx.x * 256 + threadIdx.x;
  int v = (i < M) ? deg[i] : 0;
#pragma unroll
  for (int d = 1; d < 64; d <<= 1) v += __shfl_xor(v, d, 64);
  __shared__ int ws[4];
  const int lane = threadIdx.x & 63, w = threadIdx.x >> 6;
  if (lane == 0) ws[w] = v;
  __syncthreads();
  if (threadIdx.x == 0) bsum[blockIdx.x] = ws[0] + ws[1] + ws[2] + ws[3];
}

// single block; NB <= 256. boff = exclusive scan of bsum; *startM = total.
__global__ __launch_bounds__(256)
void scan_bsum(const int* __restrict__ bsum, int* __restrict__ boff,
               int* __restrict__ startM, int NB) {
  const int t = threadIdx.x, lane = t & 63, w = t >> 6;
  const int v = (t < NB) ? bsum[t] : 0;
  int s = v;
#pragma unroll
  for (int d = 1; d < 64; d <<= 1) {
    int u = __shfl_up(s, d, 64);
    if (lane >= d) s += u;
  }
  __shared__ int ws[4];
  if (lane == 63) ws[w] = s;
  __syncthreads();
  int add = 0;
  for (int k = 0; k < w; ++k) add += ws[k];
  s += add;
  if (t < NB) boff[t] = s - v;
  if (t == NB - 1) *startM = s;
}

__global__ __launch_bounds__(256)
void scan_final(const int* __restrict__ deg, const int* __restrict__ boff,
                int* __restrict__ start, int* __restrict__ cursor, int M) {
  const int b = blockIdx.x, t = threadIdx.x, i = b * 256 + t;
  const int lane = t & 63, w = t >> 6;
  const int v = (i < M) ? deg[i] : 0;
  int s = v;
#pragma unroll
  for (int d = 1; d < 64; d <<= 1) {
    int u = __shfl_up(s, d, 64);
    if (lane >= d) s += u;
  }
  __shared__ int ws[4];
  if (lane == 63) ws[w] = s;
  __syncthreads();
  int add = boff[b];
  for (int k = 0; k < w; ++k) add += ws[k];
  const int excl = s - v + add;
  if (i < M) { start[i] = excl; cursor[i] = excl; }
}

__global__ void csr_fill(const int* __restrict__ src32, const int* __restrict__ dst32,
                         int* __restrict__ cursor, int* __restrict__ csr, int E) {
  int e = blockIdx.x * blockDim.x + threadIdx.x;
  if (e >= E) return;
  int pos = atomicAdd(&cursor[dst32[e]], 1);
  csr[pos] = src32[e];
}

// one wave per dst node. qkv row layout: q(256 cols) | kv-interleaved(512):
// lane l: q dims 4l..4l+3 at +lane*4; {k,v} dims 4l..4l+3 packed at +256+lane*8.
__global__ __launch_bounds__(256)
void attn_gather(const int* __restrict__ csr, const int* __restrict__ start,
                 const unsigned short* __restrict__ qkv,
                 unsigned short* __restrict__ aggb, int M) {
  const int wid = threadIdx.x >> 6, lane = threadIdx.x & 63;
  const int row = blockIdx.x * 4 + wid;
  if (row >= M) return;
  const ushort4 q4 = *(const ushort4*)&qkv[(size_t)row * 768 + lane * 4];
  const float SC = 0.17677669529663687f;  // 32^-0.5, folded into q
  const float qf0 = bf2f(q4.x) * SC, qf1 = bf2f(q4.y) * SC;
  const float qf2 = bf2f(q4.z) * SC, qf3 = bf2f(q4.w) * SC;
  const int b = start[row], e = start[row + 1];
  float den = 0.f, a0 = 0.f, a1 = 0.f, a2 = 0.f, a3 = 0.f;
#pragma unroll 2
  for (int i = b; i < e; ++i) {
    const int src = csr[i];
    const u16x8 kv = *(const u16x8*)&qkv[(size_t)src * 768 + 256 + lane * 8];
    float s = qf0 * bf2f(kv[0]) + qf1 * bf2f(kv[1]) +
              qf2 * bf2f(kv[2]) + qf3 * bf2f(kv[3]);
    s += __shfl_xor(s, 1, 64);
    s += __shfl_xor(s, 2, 64);
    s += __shfl_xor(s, 4, 64);
    const float ex = expf(s);
    den += ex;
    a0 += ex * bf2f(kv[4]); a1 += ex * bf2f(kv[5]);
    a2 += ex * bf2f(kv[6]); a3 += ex * bf2f(kv[7]);
  }
  const float inv = den > 0.f ? 1.f / den : 0.f;
  ushort4 r;
  r.x = f2bf(a0 * inv); r.y = f2bf(a1 * inv);
  r.z = f2bf(a2 * inv); r.w = f2bf(a3 * inv);
  *(ushort4*)&aggb[(size_t)row * 256 + lane * 4] = r;
}

// ---------------------------------------------------------------------------
extern "C" void kernel_launch(void* const* d_in, const int* in_sizes, int n_in,
                              void* d_out, int out_size, void* d_ws, size_t ws_size,
                              hipStream_t stream) {
  (void)n_in;
  const float* x  = (const float*)d_in[0];
  const float* c  = (const float*)d_in[1];
  const void*  ei = d_in[2];
  const float* Wq = (const float*)d_in[3];
  const float* bq = (const float*)d_in[4];
  const float* Wk = (const float*)d_in[5];
  const float* bk = (const float*)d_in[6];
  const float* Wv = (const float*)d_in[7];
  const float* bv = (const float*)d_in[8];
  const float* Wo = (const float*)d_in[9];
  const float* bo = (const float*)d_in[10];
  const float* W1 = (const float*)d_in[11];
  const float* b1 = (const float*)d_in[12];
  const float* W2 = (const float*)d_in[13];
  const float* b2 = (const float*)d_in[14];
  const float* Wc = (const float*)d_in[15];
  const float* bc = (const float*)d_in[16];

  const int M = in_sizes[0] / 256;   // 50000
  const int E = in_sizes[2] / 2;     // 800000

  char* ws = (char*)d_ws;
  size_t off = 0;
  auto carve = [&](size_t bytes) {
    char* p = ws + off;
    off = (off + bytes + 255) & ~(size_t)255;
    return p;
  };
  // persistent
  unsigned short* modv = (unsigned short*)carve((size_t)M * 1536 * 2);  // 153.6MB
  // multi-use region D (76.8MB): cs/qkv/h2-half at +0; aggb/hbuf2 at +51.2MB
  char* D = carve((size_t)M * 768 * 2);
  unsigned short* cs    = (unsigned short*)D;                       // [M,256]b
  unsigned short* qkv   = (unsigned short*)D;                       // [M,768]b
  unsigned short* h2h   = (unsigned short*)D;                       // [M,512]b
  unsigned short* aggb  = (unsigned short*)(D + (size_t)M * 1024);  // [M,256]b
  unsigned short* hbuf2 = (unsigned short*)(D + (size_t)M * 1024);  // [M,256]b
  unsigned short* Wct   = (unsigned short*)carve((size_t)1536 * 256 * 2);
  unsigned short* Wqkvt = (unsigned short*)carve((size_t)768 * 256 * 2);
  unsigned short* Wot   = (unsigned short*)carve((size_t)256 * 256 * 2);
  unsigned short* W1t   = (unsigned short*)carve((size_t)1024 * 256 * 2);
  unsigned short* W2tA  = (unsigned short*)carve((size_t)256 * 512 * 2);
  unsigned short* W2tB  = (unsigned short*)carve((size_t)256 * 512 * 2);
  float* bqkv = (float*)carve(768 * 4);
  float* zbias = (float*)carve(256 * 4);
  int* flag = (int*)carve(256);
  // CSR buffers
  int* src32  = (int*)carve((size_t)E * 4);
  int* dst32  = (int*)carve((size_t)E * 4);
  int* deg    = (int*)carve((size_t)(M + 4) * 4);
  int* startp = (int*)carve((size_t)(M + 4) * 4);
  int* cursor = (int*)carve((size_t)(M + 4) * 4);
  int* csr    = (int*)carve((size_t)E * 4);
  int* bsum   = (int*)carve(1024);   // 196 block sums
  int* boff   = (int*)carve(1024);

  // in-d_out aliases
  unsigned short* hbuf = (unsigned short*)d_out;  // [M,256]b, dead before Wo
  float* xout = (float*)d_out;

  if (off > ws_size) {
    sentinel_fill<<<2048, 256, 0, stream>>>((float*)d_out, (long)out_size,
                                            (float)ws_size);
    return;
  }

  const int tb = 256;
  const int EB = (E + tb - 1) / tb;
  const int SB = (M + 255) / 256;  // scan blocks (196)
  detect_i64<<<1, 256, 0, stream>>>((const unsigned int*)ei, E, flag);
  // --- CSR build ---
  fill_zero4<<<64, 256, 0, stream>>>((float*)deg, (long)(M + 4) / 4);
  conv_hist<<<EB, tb, 0, stream>>>(ei, flag, src32, dst32, deg, E);
  block_sum<<<SB, 256, 0, stream>>>(deg, bsum, M);
  scan_bsum<<<1, 256, 0, stream>>>(bsum, boff, startp + M, SB);
  scan_final<<<SB, 256, 0, stream>>>(deg, boff, startp, cursor, M);
  csr_fill<<<EB, tb, 0, stream>>>(src32, dst32, cursor, csr, E);

  // weight transposes -> bf16 [N,K] row-major (kv-interleaved for Wk/Wv)
  transpose_cast<<<(256 * 1536 + tb - 1) / tb, tb, 0, stream>>>(Wc, Wct, 1536, 0, 256, 0);
  transpose_cast<<<(256 * 256 + tb - 1) / tb, tb, 0, stream>>>(Wq, Wqkvt, 256, 0, 256, 0);
  transpose_cast<<<(256 * 256 + tb - 1) / tb, tb, 0, stream>>>(Wk, Wqkvt + 256 * 256, 256, 0, 256, 1);
  transpose_cast<<<(256 * 256 + tb - 1) / tb, tb, 0, stream>>>(Wv, Wqkvt + 256 * 256, 256, 0, 256, 2);
  transpose_cast<<<(256 * 256 + tb - 1) / tb, tb, 0, stream>>>(Wo, Wot, 256, 0, 256, 0);
  transpose_cast<<<(256 * 1024 + tb - 1) / tb, tb, 0, stream>>>(W1, W1t, 1024, 0, 256, 0);
  transpose_cast<<<(512 * 256 + tb - 1) / tb, tb, 0, stream>>>(W2, W2tA, 256, 0, 512, 0);
  transpose_cast<<<(512 * 256 + tb - 1) / tb, tb, 0, stream>>>(W2, W2tB, 256, 512, 512, 0);
  concat_bias<<<3, tb, 0, stream>>>(bq, bk, bv, bqkv);
  fill_zero4<<<1, 64, 0, stream>>>(zbias, 64);   // 64 float4 = 256 floats

  // XCD-grouped 1-D grid size
  auto gsz = [](int Mz, int Nz) {
    int MT = (Mz + 127) / 128, NT = Nz / 128;
    return 8 * ((MT + 7) / 8) * NT;
  };
  // cs = bf16(silu(c))
  silu_cast<<<(M * 64 + tb - 1) / tb, tb, 0, stream>>>(c, cs, M * 64);
  // modv = cs @ Wc + bc            [M,1536]
  gemm_bf16<0><<<gsz(M, 1536), 256, 0, stream>>>(cs, Wct, bc, nullptr, nullptr,
                                                 modv, M, 1536, 256);
  // hbuf(d_out) = modulate(ln(x), shift_msa, scale_msa)
  ln_modulate<<<(M + 3) / 4, 256, 0, stream>>>(x, modv, hbuf, M, 0, 1);
  // qkv = hbuf @ [Wq|kv-interleaved Wk,Wv] + bias   [M,768]
  gemm_bf16<0><<<gsz(M, 768), 256, 0, stream>>>(hbuf, Wqkvt, bqkv, nullptr, nullptr,
                                                qkv, M, 768, 256);
  // aggb = softmax-weighted gather per dst (registers; no atomics)
  attn_gather<<<(M + 3) / 4, 256, 0, stream>>>(csr, startp, qkv, aggb, M);
  // x1(d_out) = x + gate_msa * (aggb @ Wo + bo)
  gemm_bf16<2><<<gsz(M, 256), 256, 0, stream>>>(aggb, Wot, bo, x, modv + 512,
                                                xout, M, 256, 256);
  // hbuf2 = modulate(ln(x1), shift_mlp, scale_mlp)   (overwrites aggb: dead)
  ln_modulate<<<(M + 3) / 4, 256, 0, stream>>>(xout, modv, hbuf2, M, 3, 4);
  // MLP split into two K=512 halves to halve h2 storage:
  gemm_bf16<1><<<gsz(M, 512), 256, 0, stream>>>(hbuf2, W1t, b1, nullptr, nullptr,
                                                h2h, M, 512, 256);
  gemm_bf16<2><<<gsz(M, 256), 256, 0, stream>>>(h2h, W2tA, zbias, xout, modv + 1280,
                                                xout, M, 256, 512);
  gemm_bf16<1><<<gsz(M, 512), 256, 0, stream>>>(hbuf2, W1t + 512 * 256, b1 + 512,
                                                nullptr, nullptr, h2h, M, 512, 256);
  gemm_bf16<2><<<gsz(M, 256), 256, 0, stream>>>(h2h, W2tB, b2, xout, modv + 1280,
                                                xout, M, 256, 512);
}

// Round 7
// 645.356 us; speedup vs baseline: 5.0085x; 1.0548x over previous
//
#include <hip/hip_runtime.h>

// ---------------------------------------------------------------------------
// DiT graph-attention block, MI355X (gfx950).
// R7 = R6 with the epilogue repack-store indexing fixed:
//   64 rows x 128 cols = 1024 16B units -> row = u>>4, col8 = (u&15)*8.
//   (R6 used u>>3/(u&7)*8: read past the repack region and never stored
//    columns 64..127 -> absmax 0.33.)
// ---------------------------------------------------------------------------

typedef __attribute__((ext_vector_type(8))) short bf16x8;
typedef __attribute__((ext_vector_type(8))) unsigned short u16x8;
typedef __attribute__((ext_vector_type(4))) float f32x4;

__device__ __forceinline__ float bf2f(unsigned short u) {
  union { float f; unsigned int i; } x; x.i = ((unsigned int)u) << 16; return x.f;
}
__device__ __forceinline__ unsigned short f2bf(float f) {
  union { float f; unsigned int i; } x; x.f = f;
  unsigned int r = x.i + 0x7fffu + ((x.i >> 16) & 1u);  // RNE
  return (unsigned short)(r >> 16);
}

__device__ __forceinline__ void gload_lds16(const void* g, void* l) {
  __builtin_amdgcn_global_load_lds(
      (const __attribute__((address_space(1))) void*)g,
      (__attribute__((address_space(3))) void*)l, 16, 0, 0);
}

// ---------------------------------------------------------------------------
// Unified bf16 GEMM:  out = epilogue(A[M,K](lda) @ Bt[N,K]^T + bias)
// XCD-grouped 1-D grid (pid%8 = XCD; col-siblings consecutive on one XCD).
// EPI 0: out bf16 = acc+bias               (coalesced LDS-repack stores, ldo)
// EPI 1: out bf16 = gelu_tanh(acc+bias)    (coalesced LDS-repack stores, ldo)
// EPI 2: out f32  = xin + gate*(acc+bias)  (gate bf16 stride 1536, xin ldo)
// ---------------------------------------------------------------------------
template <int EPI>
__global__ __launch_bounds__(256)
void gemm_bf16(const unsigned short* __restrict__ A,
               const unsigned short* __restrict__ Bt,
               const float* __restrict__ bias,
               const float* __restrict__ xin,
               const unsigned short* __restrict__ gate,
               void* __restrict__ out,
               int M, int N, int K, int lda, int ldo) {
  const int NT = N >> 7;
  const int MT = (M + 127) >> 7;
  const int pid = blockIdx.x;
  const int xcd = pid & 7;
  const int j = pid >> 3;
  const int rb = xcd + 8 * (j / NT);
  const int cb = j - (j / NT) * NT;
  if (rb >= MT) return;  // uniform across block

  __shared__ unsigned short At[128 * 64];
  __shared__ unsigned short Bs[128 * 64];
  const int tid = threadIdx.x;
  const int wid = tid >> 6;
  const int lane = tid & 63;
  const int l15 = lane & 15, l4 = lane >> 4;
  const int row0 = rb * 128, col0 = cb * 128;
  const int wr = (wid >> 1) * 64, wc = (wid & 1) * 64;

  f32x4 acc[4][4];
  const f32x4 zf = {0.f, 0.f, 0.f, 0.f};
  for (int m = 0; m < 4; ++m)
    for (int n = 0; n < 4; ++n) acc[m][n] = zf;

  for (int kt = 0; kt < K; kt += 64) {
    __syncthreads();
#pragma unroll
    for (int s = 0; s < 4; ++s) {
      const int p = s * 4096 + tid * 16;           // physical byte in tile
      const int r = p >> 7;                        // tile row
      const int scb = (p & 127) ^ ((r & 7) << 4);  // swizzled source col byte
      int gr = row0 + r; gr = gr < M ? gr : M - 1;
      gload_lds16((const char*)A + ((size_t)gr * lda + kt) * 2 + scb,
                  (char*)At + s * 4096 + wid * 1024);
      const int gc = col0 + r;                     // N multiple of 128
      gload_lds16((const char*)Bt + ((size_t)gc * K + kt) * 2 + scb,
                  (char*)Bs + s * 4096 + wid * 1024);
    }
    __syncthreads();
#pragma unroll
    for (int kk = 0; kk < 64; kk += 32) {
      bf16x8 af[4], bfr[4];
#pragma unroll
      for (int m = 0; m < 4; ++m) {
        const int r = wr + m * 16 + l15;
        const int cb2 = ((kk + l4 * 8) * 2) ^ ((r & 7) << 4);
        af[m] = *(const bf16x8*)((const char*)At + r * 128 + cb2);
      }
#pragma unroll
      for (int n = 0; n < 4; ++n) {
        const int r = wc + n * 16 + l15;
        const int cb2 = ((kk + l4 * 8) * 2) ^ ((r & 7) << 4);
        bfr[n] = *(const bf16x8*)((const char*)Bs + r * 128 + cb2);
      }
#pragma unroll
      for (int m = 0; m < 4; ++m)
#pragma unroll
        for (int n = 0; n < 4; ++n)
          acc[m][n] = __builtin_amdgcn_mfma_f32_16x16x32_bf16(af[m], bfr[n],
                                                              acc[m][n], 0, 0, 0);
    }
  }

  // C/D layout: col=lane&15, row=(lane>>4)*4+reg   [guide §3, m89/m91]
  if (EPI == 2) {
#pragma unroll
    for (int m = 0; m < 4; ++m)
#pragma unroll
      for (int jj = 0; jj < 4; ++jj) {
        const int gr = row0 + wr + m * 16 + l4 * 4 + jj;
        if (gr >= M) continue;
#pragma unroll
        for (int n = 0; n < 4; ++n) {
          const int gc = col0 + wc + n * 16 + l15;
          const float v = acc[m][n][jj] + bias[gc];
          const float gt = bf2f(gate[(size_t)gr * 1536 + gc]);
          ((float*)out)[(size_t)gr * ldo + gc] =
              xin[(size_t)gr * ldo + gc] + gt * v;
        }
      }
  } else {
    // bf16 outputs: repack 64-row halves through At, store bf16x8 coalesced
    __syncthreads();  // all LDS reads of K-loop done
#pragma unroll
    for (int half = 0; half < 2; ++half) {
      if ((wid >> 1) == half) {
#pragma unroll
        for (int m = 0; m < 4; ++m)
#pragma unroll
          for (int jj = 0; jj < 4; ++jj) {
            const int row_l = m * 16 + l4 * 4 + jj;  // 0..63
#pragma unroll
            for (int n = 0; n < 4; ++n) {
              const int col = wc + n * 16 + l15;     // 0..127
              float v = acc[m][n][jj] + bias[col0 + col];
              if (EPI == 1) {
                float t = tanhf(0.7978845608f * (v + 0.044715f * v * v * v));
                v = 0.5f * v * (1.f + t);
              }
              At[row_l * 128 + col] = f2bf(v);
            }
          }
      }
      __syncthreads();
#pragma unroll
      for (int p = 0; p < 4; ++p) {
        const int u = p * 256 + tid;        // 16B unit id, 1024 total
        const int row_l = u >> 4;           // 64 rows, 16 units each
        const int col8 = (u & 15) * 8;
        const int gr = row0 + half * 64 + row_l;
        if (gr < M) {
          const bf16x8 vv = *(const bf16x8*)&At[row_l * 128 + col8];
          *(bf16x8*)((unsigned short*)out + (size_t)gr * ldo + col0 + col8) = vv;
        }
      }
      __syncthreads();
    }
  }
}

// ---------------------------------------------------------------------------
// helpers
// ---------------------------------------------------------------------------
// n4 = number of FLOAT4 (16-byte) elements to zero
__global__ void fill_zero4(float* p, long n4) {
  long i = (long)blockIdx.x * blockDim.x + threadIdx.x;
  const long st = (long)gridDim.x * blockDim.x;
  const float4 z = make_float4(0.f, 0.f, 0.f, 0.f);
  for (; i < n4; i += st) ((float4*)p)[i] = z;
}

__global__ void sentinel_fill(float* o, long n, float v) {
  long i = (long)blockIdx.x * blockDim.x + threadIdx.x;
  const long st = (long)gridDim.x * blockDim.x;
  for (; i < n; i += st) o[i] = (i == 0) ? v : 0.f;
}

// fused weight transposes -> bf16 [N,K] row-major; kv-interleave for Wk/Wv
__global__ void prep_weights(const float* __restrict__ Wc, const float* __restrict__ Wq,
                             const float* __restrict__ Wk, const float* __restrict__ Wv,
                             const float* __restrict__ Wo, const float* __restrict__ W1,
                             const float* __restrict__ W2,
                             unsigned short* __restrict__ Wct,
                             unsigned short* __restrict__ Wqkvt,
                             unsigned short* __restrict__ Wot,
                             unsigned short* __restrict__ W1t,
                             unsigned short* __restrict__ W2t) {
  const int job = blockIdx.y;
  const int i = blockIdx.x * 256 + threadIdx.x;
  const float* W; unsigned short* Wt; int N, kc, mode = 0;
  switch (job) {
    case 0: W = Wc; Wt = Wct; N = 1536; kc = 256; break;
    case 1: W = Wq; Wt = Wqkvt; N = 256; kc = 256; break;
    case 2: W = Wk; Wt = Wqkvt + 256 * 256; N = 256; kc = 256; mode = 1; break;
    case 3: W = Wv; Wt = Wqkvt + 256 * 256; N = 256; kc = 256; mode = 2; break;
    case 4: W = Wo; Wt = Wot; N = 256; kc = 256; break;
    case 5: W = W1; Wt = W1t; N = 1024; kc = 256; break;
    default: W = W2; Wt = W2t; N = 256; kc = 1024; break;
  }
  if (i >= N * kc) return;
  const int kk = i / N, n = i - kk * N;
  int r = n;
  if (mode == 1) r = ((n >> 2) << 3) + (n & 3);
  else if (mode == 2) r = ((n >> 2) << 3) + 4 + (n & 3);
  Wt[(size_t)r * kc + kk] = f2bf(W[(size_t)kk * N + n]);
}

// bias concat with the same kv interleave
__global__ void concat_bias(const float* __restrict__ bq, const float* __restrict__ bk,
                            const float* __restrict__ bv, float* __restrict__ o) {
  int i = blockIdx.x * blockDim.x + threadIdx.x;
  if (i < 256) o[i] = bq[i];
  else if (i < 512) { int d = i - 256; o[256 + ((d >> 2) << 3) + (d & 3)] = bk[d]; }
  else if (i < 768) { int d = i - 512; o[256 + ((d >> 2) << 3) + 4 + (d & 3)] = bv[d]; }
}

__global__ void silu_cast(const float* __restrict__ c, unsigned short* __restrict__ o,
                          int total4) {
  int i = blockIdx.x * blockDim.x + threadIdx.x;
  if (i >= total4) return;
  float4 v = *(const float4*)&c[(size_t)i * 4];
  ushort4 r;
  r.x = f2bf(v.x / (1.f + expf(-v.x)));
  r.y = f2bf(v.y / (1.f + expf(-v.y)));
  r.z = f2bf(v.z / (1.f + expf(-v.z)));
  r.w = f2bf(v.w / (1.f + expf(-v.w)));
  *(ushort4*)&o[(size_t)i * 4] = r;
}

// one wave per row: h = ((x-mean)*rstd)*(1+scale)+shift -> bf16
__global__ void ln_modulate(const float* __restrict__ xin,
                            const unsigned short* __restrict__ modv,
                            unsigned short* __restrict__ hout,
                            int M, int cshift, int cscale) {
  const int wid = threadIdx.x >> 6, lane = threadIdx.x & 63;
  const int row = blockIdx.x * 4 + wid;
  if (row >= M) return;
  const float4 x4 = *(const float4*)&xin[(size_t)row * 256 + lane * 4];
  float s = x4.x + x4.y + x4.z + x4.w;
  float ss = x4.x * x4.x + x4.y * x4.y + x4.z * x4.z + x4.w * x4.w;
#pragma unroll
  for (int m = 1; m < 64; m <<= 1) {
    s += __shfl_xor(s, m, 64);
    ss += __shfl_xor(ss, m, 64);
  }
  const float mean = s * (1.f / 256.f);
  const float var = ss * (1.f / 256.f) - mean * mean;
  const float rstd = rsqrtf(var + 1e-6f);
  const ushort4 sh4 = *(const ushort4*)&modv[(size_t)row * 1536 + cshift * 256 + lane * 4];
  const ushort4 sc4 = *(const ushort4*)&modv[(size_t)row * 1536 + cscale * 256 + lane * 4];
  ushort4 o;
  o.x = f2bf((x4.x - mean) * rstd * (1.f + bf2f(sc4.x)) + bf2f(sh4.x));
  o.y = f2bf((x4.y - mean) * rstd * (1.f + bf2f(sc4.y)) + bf2f(sh4.y));
  o.z = f2bf((x4.z - mean) * rstd * (1.f + bf2f(sc4.z)) + bf2f(sh4.z));
  o.w = f2bf((x4.w - mean) * rstd * (1.f + bf2f(sc4.w)) + bf2f(sh4.w));
  *(ushort4*)&hout[(size_t)row * 256 + lane * 4] = o;
}

// detect int64 vs int32 edge_index
__global__ void detect_i64(const unsigned int* __restrict__ e, int E, int* flag) {
  __shared__ int bad;
  if (threadIdx.x == 0) bad = 0;
  __syncthreads();
  const int n = E < 256 ? E : 256;
  if ((int)threadIdx.x < n && e[2 * threadIdx.x + 1] != 0u) atomicAdd(&bad, 1);
  __syncthreads();
  if (threadIdx.x == 0) *flag = (bad == 0);
}

// unpack edge_index -> src32/dst32 and histogram dst degree (fused)
__global__ void conv_hist(const void* __restrict__ ei, const int* __restrict__ flag,
                          int* __restrict__ src32, int* __restrict__ dst32,
                          int* __restrict__ deg, int E) {
  int e = blockIdx.x * blockDim.x + threadIdx.x;
  if (e >= E) return;
  int s, d;
  if (*flag) {
    const long long* p = (const long long*)ei;
    s = (int)p[e]; d = (int)p[E + e];
  } else {
    const int* p = (const int*)ei;
    s = p[e]; d = p[E + e];
  }
  src32[e] = s; dst32[e] = d;
  atomicAdd(&deg[d], 1);
}

// 3-phase scan
__global__ __launch_bounds__(256)
void block_sum(const int* __restrict__ deg, int* __restrict__ bsum, int M) {
  int i = blockIdx.x * 256 + threadIdx.x;
  int v = (i < M) ? deg[i] : 0;
#pragma unroll
  for (int d = 1; d < 64; d <<= 1) v += __shfl_xor(v, d, 64);
  __shared__ int ws[4];
  const int lane = threadIdx.x & 63, w = threadIdx.x >> 6;
  if (lane == 0) ws[w] = v;
  __syncthreads();
  if (threadIdx.x == 0) bsum[blockIdx.x] = ws[0] + ws[1] + ws[2] + ws[3];
}

__global__ __launch_bounds__(256)
void scan_bsum(const int* __restrict__ bsum, int* __restrict__ boff,
               int* __restrict__ startM, int NB) {
  const int t = threadIdx.x, lane = t & 63, w = t >> 6;
  const int v = (t < NB) ? bsum[t] : 0;
  int s = v;
#pragma unroll
  for (int d = 1; d < 64; d <<= 1) {
    int u = __shfl_up(s, d, 64);
    if (lane >= d) s += u;
  }
  __shared__ int ws[4];
  if (lane == 63) ws[w] = s;
  __syncthreads();
  int add = 0;
  for (int k = 0; k < w; ++k) add += ws[k];
  s += add;
  if (t < NB) boff[t] = s - v;
  if (t == NB - 1) *startM = s;
}

__global__ __launch_bounds__(256)
void scan_final(const int* __restrict__ deg, const int* __restrict__ boff,
                int* __restrict__ start, int* __restrict__ cursor, int M) {
  const int b = blockIdx.x, t = threadIdx.x, i = b * 256 + t;
  const int lane = t & 63, w = t >> 6;
  const int v = (i < M) ? deg[i] : 0;
  int s = v;
#pragma unroll
  for (int d = 1; d < 64; d <<= 1) {
    int u = __shfl_up(s, d, 64);
    if (lane >= d) s += u;
  }
  __shared__ int ws[4];
  if (lane == 63) ws[w] = s;
  __syncthreads();
  int add = boff[b];
  for (int k = 0; k < w; ++k) add += ws[k];
  const int excl = s - v + add;
  if (i < M) { start[i] = excl; cursor[i] = excl; }
}

__global__ void csr_fill(const int* __restrict__ src32, const int* __restrict__ dst32,
                         int* __restrict__ cursor, int* __restrict__ csr, int E) {
  int e = blockIdx.x * blockDim.x + threadIdx.x;
  if (e >= E) return;
  int pos = atomicAdd(&cursor[dst32[e]], 1);
  csr[pos] = src32[e];
}

// one wave per dst node. qkv row: q(256) | kv-interleaved(512).
__global__ __launch_bounds__(256)
void attn_gather(const int* __restrict__ csr, const int* __restrict__ start,
                 const unsigned short* __restrict__ qkv,
                 unsigned short* __restrict__ aggb, int M) {
  const int wid = threadIdx.x >> 6, lane = threadIdx.x & 63;
  const int row = blockIdx.x * 4 + wid;
  if (row >= M) return;
  const ushort4 q4 = *(const ushort4*)&qkv[(size_t)row * 768 + lane * 4];
  const float SC = 0.17677669529663687f;  // 32^-0.5, folded into q
  const float qf0 = bf2f(q4.x) * SC, qf1 = bf2f(q4.y) * SC;
  const float qf2 = bf2f(q4.z) * SC, qf3 = bf2f(q4.w) * SC;
  const int b = start[row], e = start[row + 1];
  float den = 0.f, a0 = 0.f, a1 = 0.f, a2 = 0.f, a3 = 0.f;
#pragma unroll 4
  for (int i = b; i < e; ++i) {
    const int src = csr[i];
    const u16x8 kv = *(const u16x8*)&qkv[(size_t)src * 768 + 256 + lane * 8];
    float s = qf0 * bf2f(kv[0]) + qf1 * bf2f(kv[1]) +
              qf2 * bf2f(kv[2]) + qf3 * bf2f(kv[3]);
    s += __shfl_xor(s, 1, 64);
    s += __shfl_xor(s, 2, 64);
    s += __shfl_xor(s, 4, 64);
    const float ex = expf(s);
    den += ex;
    a0 += ex * bf2f(kv[4]); a1 += ex * bf2f(kv[5]);
    a2 += ex * bf2f(kv[6]); a3 += ex * bf2f(kv[7]);
  }
  const float inv = den > 0.f ? 1.f / den : 0.f;
  ushort4 r;
  r.x = f2bf(a0 * inv); r.y = f2bf(a1 * inv);
  r.z = f2bf(a2 * inv); r.w = f2bf(a3 * inv);
  *(ushort4*)&aggb[(size_t)row * 256 + lane * 4] = r;
}

// ---------------------------------------------------------------------------
extern "C" void kernel_launch(void* const* d_in, const int* in_sizes, int n_in,
                              void* d_out, int out_size, void* d_ws, size_t ws_size,
                              hipStream_t stream) {
  (void)n_in;
  const float* x  = (const float*)d_in[0];
  const float* c  = (const float*)d_in[1];
  const void*  ei = d_in[2];
  const float* Wq = (const float*)d_in[3];
  const float* bq = (const float*)d_in[4];
  const float* Wk = (const float*)d_in[5];
  const float* bk = (const float*)d_in[6];
  const float* Wv = (const float*)d_in[7];
  const float* bv = (const float*)d_in[8];
  const float* Wo = (const float*)d_in[9];
  const float* bo = (const float*)d_in[10];
  const float* W1 = (const float*)d_in[11];
  const float* b1 = (const float*)d_in[12];
  const float* W2 = (const float*)d_in[13];
  const float* b2 = (const float*)d_in[14];
  const float* Wc = (const float*)d_in[15];
  const float* bc = (const float*)d_in[16];

  const int M = in_sizes[0] / 256;   // 50000
  const int E = in_sizes[2] / 2;     // 800000

  char* ws = (char*)d_ws;
  size_t off = 0;
  auto carve = [&](size_t bytes) {
    char* p = ws + off;
    off = (off + bytes + 255) & ~(size_t)255;
    return p;
  };
  // persistent: modv [M,1536]b; cols 0..1024 reused as h2 (ldo=1536) after ln2
  unsigned short* modv = (unsigned short*)carve((size_t)M * 1536 * 2);  // 153.6MB
  // region D (M*1536 bytes): cs [M,256]b -> qkv [M,768]b -> X1 [M,256]f32
  char* D = carve((size_t)M * 1536);
  unsigned short* cs  = (unsigned short*)D;
  unsigned short* qkv = (unsigned short*)D;
  float* X1 = (float*)D;
  unsigned short* Wct   = (unsigned short*)carve((size_t)1536 * 256 * 2);
  unsigned short* Wqkvt = (unsigned short*)carve((size_t)768 * 256 * 2);
  unsigned short* Wot   = (unsigned short*)carve((size_t)256 * 256 * 2);
  unsigned short* W1t   = (unsigned short*)carve((size_t)1024 * 256 * 2);
  unsigned short* W2t   = (unsigned short*)carve((size_t)256 * 1024 * 2);
  float* bqkv = (float*)carve(768 * 4);
  int* flag = (int*)carve(256);
  // CSR buffers
  int* src32  = (int*)carve((size_t)E * 4);
  int* dst32  = (int*)carve((size_t)E * 4);
  int* deg    = (int*)carve((size_t)(M + 4) * 4);
  int* startp = (int*)carve((size_t)(M + 4) * 4);
  int* cursor = (int*)carve((size_t)(M + 4) * 4);
  int* csr    = (int*)carve((size_t)E * 4);
  int* bsum   = (int*)carve(1024);
  int* boff   = (int*)carve(1024);

  // d_out (M*256 f32 = M*1024 bytes) aliases:
  //   lower half: hbuf (ln1 out) then hbuf2 (ln2 out)   [M,256]b each
  //   upper half: aggb (attn out)                        [M,256]b
  unsigned short* hbuf  = (unsigned short*)d_out;
  unsigned short* hbuf2 = (unsigned short*)d_out;
  unsigned short* aggb  = (unsigned short*)((char*)d_out + (size_t)M * 512);
  float* xout = (float*)d_out;

  if (off > ws_size) {
    sentinel_fill<<<2048, 256, 0, stream>>>((float*)d_out, (long)out_size,
                                            (float)ws_size);
    return;
  }

  const int tb = 256;
  const int EB = (E + tb - 1) / tb;
  const int SB = (M + 255) / 256;
  detect_i64<<<1, 256, 0, stream>>>((const unsigned int*)ei, E, flag);
  // --- CSR build ---
  fill_zero4<<<64, 256, 0, stream>>>((float*)deg, (long)(M + 4) / 4);
  conv_hist<<<EB, tb, 0, stream>>>(ei, flag, src32, dst32, deg, E);
  block_sum<<<SB, 256, 0, stream>>>(deg, bsum, M);
  scan_bsum<<<1, 256, 0, stream>>>(bsum, boff, startp + M, SB);
  scan_final<<<SB, 256, 0, stream>>>(deg, boff, startp, cursor, M);
  csr_fill<<<EB, tb, 0, stream>>>(src32, dst32, cursor, csr, E);

  // weights -> bf16 [N,K] (fused), bias concat
  prep_weights<<<dim3(1536, 7), 256, 0, stream>>>(Wc, Wq, Wk, Wv, Wo, W1, W2,
                                                  Wct, Wqkvt, Wot, W1t, W2t);
  concat_bias<<<3, tb, 0, stream>>>(bq, bk, bv, bqkv);

  auto gsz = [](int Mz, int Nz) {
    int MT = (Mz + 127) / 128, NT = Nz / 128;
    return 8 * ((MT + 7) / 8) * NT;
  };
  // cs = bf16(silu(c))
  silu_cast<<<(M * 64 + tb - 1) / tb, tb, 0, stream>>>(c, cs, M * 64);
  // modv = cs @ Wc + bc   [M,1536]
  gemm_bf16<0><<<gsz(M, 1536), 256, 0, stream>>>(cs, Wct, bc, nullptr, nullptr,
                                                 modv, M, 1536, 256, 256, 1536);
  // hbuf = modulate(ln(x), shift_msa, scale_msa)
  ln_modulate<<<(M + 3) / 4, 256, 0, stream>>>(x, modv, hbuf, M, 0, 1);
  // qkv = hbuf @ [Wq | kv-interleaved Wk,Wv] + bias   [M,768]
  gemm_bf16<0><<<gsz(M, 768), 256, 0, stream>>>(hbuf, Wqkvt, bqkv, nullptr, nullptr,
                                                qkv, M, 768, 256, 256, 768);
  // aggb(d_out hi) = per-dst softmax gather (no atomics)
  attn_gather<<<(M + 3) / 4, 256, 0, stream>>>(csr, startp, qkv, aggb, M);
  // X1(D) = x + gate_msa * (aggb @ Wo + bo)   [f32]
  gemm_bf16<2><<<gsz(M, 256), 256, 0, stream>>>(aggb, Wot, bo, x, modv + 512,
                                                X1, M, 256, 256, 256, 256);
  // hbuf2(d_out lo) = modulate(ln(X1), shift_mlp, scale_mlp)
  ln_modulate<<<(M + 3) / 4, 256, 0, stream>>>(X1, modv, hbuf2, M, 3, 4);
  // h2(modv cols 0..1024, ld 1536) = gelu(hbuf2 @ W1 + b1)   [M,1024]
  gemm_bf16<1><<<gsz(M, 1024), 256, 0, stream>>>(hbuf2, W1t, b1, nullptr, nullptr,
                                                 modv, M, 1024, 256, 256, 1536);
  // out(d_out) = X1 + gate_mlp * (h2 @ W2 + b2)
  gemm_bf16<2><<<gsz(M, 256), 256, 0, stream>>>(modv, W2t, b2, X1, modv + 1280,
                                                xout, M, 256, 1024, 1536, 256);
}

// Round 8
// 628.158 us; speedup vs baseline: 5.1457x; 1.0274x over previous
//
#include <hip/hip_runtime.h>

// ---------------------------------------------------------------------------
// DiT graph-attention block, MI355X (gfx950).
// R8: attn_gather software-pipelined (batch-4 kv prefetch, ~8 loads in
//     flight/wave; R7 showed VGPR=16 => MLP 1, BW stuck at 41% peak).
//     prep_weights absorbs detect/concat_bias/deg-zero (18 -> 15 launches).
// ---------------------------------------------------------------------------

typedef __attribute__((ext_vector_type(8))) short bf16x8;
typedef __attribute__((ext_vector_type(8))) unsigned short u16x8;
typedef __attribute__((ext_vector_type(4))) float f32x4;

__device__ __forceinline__ float bf2f(unsigned short u) {
  union { float f; unsigned int i; } x; x.i = ((unsigned int)u) << 16; return x.f;
}
__device__ __forceinline__ unsigned short f2bf(float f) {
  union { float f; unsigned int i; } x; x.f = f;
  unsigned int r = x.i + 0x7fffu + ((x.i >> 16) & 1u);  // RNE
  return (unsigned short)(r >> 16);
}

__device__ __forceinline__ void gload_lds16(const void* g, void* l) {
  __builtin_amdgcn_global_load_lds(
      (const __attribute__((address_space(1))) void*)g,
      (__attribute__((address_space(3))) void*)l, 16, 0, 0);
}

// ---------------------------------------------------------------------------
// Unified bf16 GEMM:  out = epilogue(A[M,K](lda) @ Bt[N,K]^T + bias)
// XCD-grouped 1-D grid (pid%8 = XCD; col-siblings consecutive on one XCD).
// EPI 0: out bf16 = acc+bias               (coalesced LDS-repack stores, ldo)
// EPI 1: out bf16 = gelu_tanh(acc+bias)    (coalesced LDS-repack stores, ldo)
// EPI 2: out f32  = xin + gate*(acc+bias)  (gate bf16 stride 1536, xin ldo)
// ---------------------------------------------------------------------------
template <int EPI>
__global__ __launch_bounds__(256)
void gemm_bf16(const unsigned short* __restrict__ A,
               const unsigned short* __restrict__ Bt,
               const float* __restrict__ bias,
               const float* __restrict__ xin,
               const unsigned short* __restrict__ gate,
               void* __restrict__ out,
               int M, int N, int K, int lda, int ldo) {
  const int NT = N >> 7;
  const int MT = (M + 127) >> 7;
  const int pid = blockIdx.x;
  const int xcd = pid & 7;
  const int j = pid >> 3;
  const int rb = xcd + 8 * (j / NT);
  const int cb = j - (j / NT) * NT;
  if (rb >= MT) return;  // uniform across block

  __shared__ unsigned short At[128 * 64];
  __shared__ unsigned short Bs[128 * 64];
  const int tid = threadIdx.x;
  const int wid = tid >> 6;
  const int lane = tid & 63;
  const int l15 = lane & 15, l4 = lane >> 4;
  const int row0 = rb * 128, col0 = cb * 128;
  const int wr = (wid >> 1) * 64, wc = (wid & 1) * 64;

  f32x4 acc[4][4];
  const f32x4 zf = {0.f, 0.f, 0.f, 0.f};
  for (int m = 0; m < 4; ++m)
    for (int n = 0; n < 4; ++n) acc[m][n] = zf;

  for (int kt = 0; kt < K; kt += 64) {
    __syncthreads();
#pragma unroll
    for (int s = 0; s < 4; ++s) {
      const int p = s * 4096 + tid * 16;           // physical byte in tile
      const int r = p >> 7;                        // tile row
      const int scb = (p & 127) ^ ((r & 7) << 4);  // swizzled source col byte
      int gr = row0 + r; gr = gr < M ? gr : M - 1;
      gload_lds16((const char*)A + ((size_t)gr * lda + kt) * 2 + scb,
                  (char*)At + s * 4096 + wid * 1024);
      const int gc = col0 + r;                     // N multiple of 128
      gload_lds16((const char*)Bt + ((size_t)gc * K + kt) * 2 + scb,
                  (char*)Bs + s * 4096 + wid * 1024);
    }
    __syncthreads();
#pragma unroll
    for (int kk = 0; kk < 64; kk += 32) {
      bf16x8 af[4], bfr[4];
#pragma unroll
      for (int m = 0; m < 4; ++m) {
        const int r = wr + m * 16 + l15;
        const int cb2 = ((kk + l4 * 8) * 2) ^ ((r & 7) << 4);
        af[m] = *(const bf16x8*)((const char*)At + r * 128 + cb2);
      }
#pragma unroll
      for (int n = 0; n < 4; ++n) {
        const int r = wc + n * 16 + l15;
        const int cb2 = ((kk + l4 * 8) * 2) ^ ((r & 7) << 4);
        bfr[n] = *(const bf16x8*)((const char*)Bs + r * 128 + cb2);
      }
#pragma unroll
      for (int m = 0; m < 4; ++m)
#pragma unroll
        for (int n = 0; n < 4; ++n)
          acc[m][n] = __builtin_amdgcn_mfma_f32_16x16x32_bf16(af[m], bfr[n],
                                                              acc[m][n], 0, 0, 0);
    }
  }

  // C/D layout: col=lane&15, row=(lane>>4)*4+reg   [guide §3, m89/m91]
  if (EPI == 2) {
#pragma unroll
    for (int m = 0; m < 4; ++m)
#pragma unroll
      for (int jj = 0; jj < 4; ++jj) {
        const int gr = row0 + wr + m * 16 + l4 * 4 + jj;
        if (gr >= M) continue;
#pragma unroll
        for (int n = 0; n < 4; ++n) {
          const int gc = col0 + wc + n * 16 + l15;
          const float v = acc[m][n][jj] + bias[gc];
          const float gt = bf2f(gate[(size_t)gr * 1536 + gc]);
          ((float*)out)[(size_t)gr * ldo + gc] =
              xin[(size_t)gr * ldo + gc] + gt * v;
        }
      }
  } else {
    // bf16 outputs: repack 64-row halves through At, store bf16x8 coalesced
    __syncthreads();  // all LDS reads of K-loop done
#pragma unroll
    for (int half = 0; half < 2; ++half) {
      if ((wid >> 1) == half) {
#pragma unroll
        for (int m = 0; m < 4; ++m)
#pragma unroll
          for (int jj = 0; jj < 4; ++jj) {
            const int row_l = m * 16 + l4 * 4 + jj;  // 0..63
#pragma unroll
            for (int n = 0; n < 4; ++n) {
              const int col = wc + n * 16 + l15;     // 0..127
              float v = acc[m][n][jj] + bias[col0 + col];
              if (EPI == 1) {
                float t = tanhf(0.7978845608f * (v + 0.044715f * v * v * v));
                v = 0.5f * v * (1.f + t);
              }
              At[row_l * 128 + col] = f2bf(v);
            }
          }
      }
      __syncthreads();
#pragma unroll
      for (int p = 0; p < 4; ++p) {
        const int u = p * 256 + tid;        // 16B unit id, 1024 total
        const int row_l = u >> 4;           // 64 rows, 16 units each
        const int col8 = (u & 15) * 8;
        const int gr = row0 + half * 64 + row_l;
        if (gr < M) {
          const bf16x8 vv = *(const bf16x8*)&At[row_l * 128 + col8];
          *(bf16x8*)((unsigned short*)out + (size_t)gr * ldo + col0 + col8) = vv;
        }
      }
      __syncthreads();
    }
  }
}

// ---------------------------------------------------------------------------
// helpers
// ---------------------------------------------------------------------------
__global__ void sentinel_fill(float* o, long n, float v) {
  long i = (long)blockIdx.x * blockDim.x + threadIdx.x;
  const long st = (long)gridDim.x * blockDim.x;
  for (; i < n; i += st) o[i] = (i == 0) ? v : 0.f;
}

// fused prep: weight transposes (kv-interleave for Wk/Wv), bias concat,
// deg zeroing, and int64-detect.  One launch, grid = dim3(1536, 10).
__global__ void prep_weights(const float* __restrict__ Wc, const float* __restrict__ Wq,
                             const float* __restrict__ Wk, const float* __restrict__ Wv,
                             const float* __restrict__ Wo, const float* __restrict__ W1,
                             const float* __restrict__ W2,
                             unsigned short* __restrict__ Wct,
                             unsigned short* __restrict__ Wqkvt,
                             unsigned short* __restrict__ Wot,
                             unsigned short* __restrict__ W1t,
                             unsigned short* __restrict__ W2t,
                             const float* __restrict__ bq, const float* __restrict__ bk,
                             const float* __restrict__ bv, float* __restrict__ bqkv,
                             int* __restrict__ deg, int Mdeg,
                             const unsigned int* __restrict__ ei_u32, int E,
                             int* __restrict__ flag) {
  const int job = blockIdx.y;
  const int i = blockIdx.x * 256 + threadIdx.x;
  if (job == 7) {  // bias concat (kv-interleaved)
    if (i < 256) bqkv[i] = bq[i];
    else if (i < 512) { int d = i - 256; bqkv[256 + ((d >> 2) << 3) + (d & 3)] = bk[d]; }
    else if (i < 768) { int d = i - 512; bqkv[256 + ((d >> 2) << 3) + 4 + (d & 3)] = bv[d]; }
    return;
  }
  if (job == 8) {  // zero deg
    if (i < Mdeg) deg[i] = 0;
    return;
  }
  if (job == 9) {  // int64 detect (block 0 only)
    if (blockIdx.x != 0) return;
    __shared__ int bad;
    if (threadIdx.x == 0) bad = 0;
    __syncthreads();
    const int n = E < 256 ? E : 256;
    if ((int)threadIdx.x < n && ei_u32[2 * threadIdx.x + 1] != 0u) atomicAdd(&bad, 1);
    __syncthreads();
    if (threadIdx.x == 0) *flag = (bad == 0);
    return;
  }
  const float* W; unsigned short* Wt; int N, kc, mode = 0;
  switch (job) {
    case 0: W = Wc; Wt = Wct; N = 1536; kc = 256; break;
    case 1: W = Wq; Wt = Wqkvt; N = 256; kc = 256; break;
    case 2: W = Wk; Wt = Wqkvt + 256 * 256; N = 256; kc = 256; mode = 1; break;
    case 3: W = Wv; Wt = Wqkvt + 256 * 256; N = 256; kc = 256; mode = 2; break;
    case 4: W = Wo; Wt = Wot; N = 256; kc = 256; break;
    case 5: W = W1; Wt = W1t; N = 1024; kc = 256; break;
    default: W = W2; Wt = W2t; N = 256; kc = 1024; break;
  }
  if (i >= N * kc) return;
  const int kk = i / N, n = i - kk * N;
  int r = n;
  if (mode == 1) r = ((n >> 2) << 3) + (n & 3);
  else if (mode == 2) r = ((n >> 2) << 3) + 4 + (n & 3);
  Wt[(size_t)r * kc + kk] = f2bf(W[(size_t)kk * N + n]);
}

__global__ void silu_cast(const float* __restrict__ c, unsigned short* __restrict__ o,
                          int total4) {
  int i = blockIdx.x * blockDim.x + threadIdx.x;
  if (i >= total4) return;
  float4 v = *(const float4*)&c[(size_t)i * 4];
  ushort4 r;
  r.x = f2bf(v.x / (1.f + expf(-v.x)));
  r.y = f2bf(v.y / (1.f + expf(-v.y)));
  r.z = f2bf(v.z / (1.f + expf(-v.z)));
  r.w = f2bf(v.w / (1.f + expf(-v.w)));
  *(ushort4*)&o[(size_t)i * 4] = r;
}

// one wave per row: h = ((x-mean)*rstd)*(1+scale)+shift -> bf16
__global__ void ln_modulate(const float* __restrict__ xin,
                            const unsigned short* __restrict__ modv,
                            unsigned short* __restrict__ hout,
                            int M, int cshift, int cscale) {
  const int wid = threadIdx.x >> 6, lane = threadIdx.x & 63;
  const int row = blockIdx.x * 4 + wid;
  if (row >= M) return;
  const float4 x4 = *(const float4*)&xin[(size_t)row * 256 + lane * 4];
  float s = x4.x + x4.y + x4.z + x4.w;
  float ss = x4.x * x4.x + x4.y * x4.y + x4.z * x4.z + x4.w * x4.w;
#pragma unroll
  for (int m = 1; m < 64; m <<= 1) {
    s += __shfl_xor(s, m, 64);
    ss += __shfl_xor(ss, m, 64);
  }
  const float mean = s * (1.f / 256.f);
  const float var = ss * (1.f / 256.f) - mean * mean;
  const float rstd = rsqrtf(var + 1e-6f);
  const ushort4 sh4 = *(const ushort4*)&modv[(size_t)row * 1536 + cshift * 256 + lane * 4];
  const ushort4 sc4 = *(const ushort4*)&modv[(size_t)row * 1536 + cscale * 256 + lane * 4];
  ushort4 o;
  o.x = f2bf((x4.x - mean) * rstd * (1.f + bf2f(sc4.x)) + bf2f(sh4.x));
  o.y = f2bf((x4.y - mean) * rstd * (1.f + bf2f(sc4.y)) + bf2f(sh4.y));
  o.z = f2bf((x4.z - mean) * rstd * (1.f + bf2f(sc4.z)) + bf2f(sh4.z));
  o.w = f2bf((x4.w - mean) * rstd * (1.f + bf2f(sc4.w)) + bf2f(sh4.w));
  *(ushort4*)&hout[(size_t)row * 256 + lane * 4] = o;
}

// unpack edge_index -> src32/dst32 and histogram dst degree (fused)
__global__ void conv_hist(const void* __restrict__ ei, const int* __restrict__ flag,
                          int* __restrict__ src32, int* __restrict__ dst32,
                          int* __restrict__ deg, int E) {
  int e = blockIdx.x * blockDim.x + threadIdx.x;
  if (e >= E) return;
  int s, d;
  if (*flag) {
    const long long* p = (const long long*)ei;
    s = (int)p[e]; d = (int)p[E + e];
  } else {
    const int* p = (const int*)ei;
    s = p[e]; d = p[E + e];
  }
  src32[e] = s; dst32[e] = d;
  atomicAdd(&deg[d], 1);
}

// 3-phase scan
__global__ __launch_bounds__(256)
void block_sum(const int* __restrict__ deg, int* __restrict__ bsum, int M) {
  int i = blockIdx.x * 256 + threadIdx.x;
  int v = (i < M) ? deg[i] : 0;
#pragma unroll
  for (int d = 1; d < 64; d <<= 1) v += __shfl_xor(v, d, 64);
  __shared__ int ws[4];
  const int lane = threadIdx.x & 63, w = threadIdx.x >> 6;
  if (lane == 0) ws[w] = v;
  __syncthreads();
  if (threadIdx.x == 0) bsum[blockIdx.x] = ws[0] + ws[1] + ws[2] + ws[3];
}

__global__ __launch_bounds__(256)
void scan_bsum(const int* __restrict__ bsum, int* __restrict__ boff,
               int* __restrict__ startM, int NB) {
  const int t = threadIdx.x, lane = t & 63, w = t >> 6;
  const int v = (t < NB) ? bsum[t] : 0;
  int s = v;
#pragma unroll
  for (int d = 1; d < 64; d <<= 1) {
    int u = __shfl_up(s, d, 64);
    if (lane >= d) s += u;
  }
  __shared__ int ws[4];
  if (lane == 63) ws[w] = s;
  __syncthreads();
  int add = 0;
  for (int k = 0; k < w; ++k) add += ws[k];
  s += add;
  if (t < NB) boff[t] = s - v;
  if (t == NB - 1) *startM = s;
}

__global__ __launch_bounds__(256)
void scan_final(const int* __restrict__ deg, const int* __restrict__ boff,
                int* __restrict__ start, int* __restrict__ cursor, int M) {
  const int b = blockIdx.x, t = threadIdx.x, i = b * 256 + t;
  const int lane = t & 63, w = t >> 6;
  const int v = (i < M) ? deg[i] : 0;
  int s = v;
#pragma unroll
  for (int d = 1; d < 64; d <<= 1) {
    int u = __shfl_up(s, d, 64);
    if (lane >= d) s += u;
  }
  __shared__ int ws[4];
  if (lane == 63) ws[w] = s;
  __syncthreads();
  int add = boff[b];
  for (int k = 0; k < w; ++k) add += ws[k];
  const int excl = s - v + add;
  if (i < M) { start[i] = excl; cursor[i] = excl; }
}

__global__ void csr_fill(const int* __restrict__ src32, const int* __restrict__ dst32,
                         int* __restrict__ cursor, int* __restrict__ csr, int E) {
  int e = blockIdx.x * blockDim.x + threadIdx.x;
  if (e >= E) return;
  int pos = atomicAdd(&cursor[dst32[e]], 1);
  csr[pos] = src32[e];
}

// one wave per dst node; software-pipelined batch-4 kv gather (up to 8 loads
// in flight per wave).  qkv row: q(256) | kv-interleaved(512).
__global__ __launch_bounds__(256)
void attn_gather(const int* __restrict__ csr, const int* __restrict__ start,
                 const unsigned short* __restrict__ qkv,
                 unsigned short* __restrict__ aggb, int M) {
  const int wid = threadIdx.x >> 6, lane = threadIdx.x & 63;
  const int row = blockIdx.x * 4 + wid;
  if (row >= M) return;
  const ushort4 q4 = *(const ushort4*)&qkv[(size_t)row * 768 + lane * 4];
  const float SC = 0.17677669529663687f;  // 32^-0.5, folded into q
  const float qf0 = bf2f(q4.x) * SC, qf1 = bf2f(q4.y) * SC;
  const float qf2 = bf2f(q4.z) * SC, qf3 = bf2f(q4.w) * SC;
  const int b0 = start[row], e0 = start[row + 1];
  float den = 0.f, a0 = 0.f, a1 = 0.f, a2 = 0.f, a3 = 0.f;

  auto LD = [&](int src) {
    return *(const u16x8*)&qkv[(size_t)src * 768 + 256 + lane * 8];
  };
#define PROC(kvv)                                                            \
  {                                                                          \
    float s = qf0 * bf2f(kvv[0]) + qf1 * bf2f(kvv[1]) +                      \
              qf2 * bf2f(kvv[2]) + qf3 * bf2f(kvv[3]);                       \
    s += __shfl_xor(s, 1, 64);                                               \
    s += __shfl_xor(s, 2, 64);                                               \
    s += __shfl_xor(s, 4, 64);                                               \
    const float ex = expf(s);                                                \
    den += ex;                                                               \
    a0 += ex * bf2f(kvv[4]); a1 += ex * bf2f(kvv[5]);                        \
    a2 += ex * bf2f(kvv[6]); a3 += ex * bf2f(kvv[7]);                        \
  }

  int i = b0;
  if (i + 4 <= e0) {
    u16x8 kA0 = LD(csr[i]), kA1 = LD(csr[i + 1]);
    u16x8 kA2 = LD(csr[i + 2]), kA3 = LD(csr[i + 3]);
    while (i + 8 <= e0) {
      const u16x8 kB0 = LD(csr[i + 4]), kB1 = LD(csr[i + 5]);
      const u16x8 kB2 = LD(csr[i + 6]), kB3 = LD(csr[i + 7]);
      PROC(kA0); PROC(kA1); PROC(kA2); PROC(kA3);
      kA0 = kB0; kA1 = kB1; kA2 = kB2; kA3 = kB3;
      i += 4;
    }
    PROC(kA0); PROC(kA1); PROC(kA2); PROC(kA3);
    i += 4;
  }
  for (; i < e0; ++i) {
    const u16x8 kv = LD(csr[i]);
    PROC(kv);
  }
#undef PROC

  const float inv = den > 0.f ? 1.f / den : 0.f;
  ushort4 r;
  r.x = f2bf(a0 * inv); r.y = f2bf(a1 * inv);
  r.z = f2bf(a2 * inv); r.w = f2bf(a3 * inv);
  *(ushort4*)&aggb[(size_t)row * 256 + lane * 4] = r;
}

// ---------------------------------------------------------------------------
extern "C" void kernel_launch(void* const* d_in, const int* in_sizes, int n_in,
                              void* d_out, int out_size, void* d_ws, size_t ws_size,
                              hipStream_t stream) {
  (void)n_in;
  const float* x  = (const float*)d_in[0];
  const float* c  = (const float*)d_in[1];
  const void*  ei = d_in[2];
  const float* Wq = (const float*)d_in[3];
  const float* bq = (const float*)d_in[4];
  const float* Wk = (const float*)d_in[5];
  const float* bk = (const float*)d_in[6];
  const float* Wv = (const float*)d_in[7];
  const float* bv = (const float*)d_in[8];
  const float* Wo = (const float*)d_in[9];
  const float* bo = (const float*)d_in[10];
  const float* W1 = (const float*)d_in[11];
  const float* b1 = (const float*)d_in[12];
  const float* W2 = (const float*)d_in[13];
  const float* b2 = (const float*)d_in[14];
  const float* Wc = (const float*)d_in[15];
  const float* bc = (const float*)d_in[16];

  const int M = in_sizes[0] / 256;   // 50000
  const int E = in_sizes[2] / 2;     // 800000

  char* ws = (char*)d_ws;
  size_t off = 0;
  auto carve = [&](size_t bytes) {
    char* p = ws + off;
    off = (off + bytes + 255) & ~(size_t)255;
    return p;
  };
  // persistent: modv [M,1536]b; cols 0..1024 reused as h2 (ldo=1536) after ln2
  unsigned short* modv = (unsigned short*)carve((size_t)M * 1536 * 2);  // 153.6MB
  // region D (M*1536 bytes): cs [M,256]b -> qkv [M,768]b -> X1 [M,256]f32
  char* D = carve((size_t)M * 1536);
  unsigned short* cs  = (unsigned short*)D;
  unsigned short* qkv = (unsigned short*)D;
  float* X1 = (float*)D;
  unsigned short* Wct   = (unsigned short*)carve((size_t)1536 * 256 * 2);
  unsigned short* Wqkvt = (unsigned short*)carve((size_t)768 * 256 * 2);
  unsigned short* Wot   = (unsigned short*)carve((size_t)256 * 256 * 2);
  unsigned short* W1t   = (unsigned short*)carve((size_t)1024 * 256 * 2);
  unsigned short* W2t   = (unsigned short*)carve((size_t)256 * 1024 * 2);
  float* bqkv = (float*)carve(768 * 4);
  int* flag = (int*)carve(256);
  // CSR buffers
  int* src32  = (int*)carve((size_t)E * 4);
  int* dst32  = (int*)carve((size_t)E * 4);
  int* deg    = (int*)carve((size_t)(M + 4) * 4);
  int* startp = (int*)carve((size_t)(M + 4) * 4);
  int* cursor = (int*)carve((size_t)(M + 4) * 4);
  int* csr    = (int*)carve((size_t)E * 4);
  int* bsum   = (int*)carve(1024);
  int* boff   = (int*)carve(1024);

  // d_out (M*256 f32 = M*1024 bytes) aliases:
  //   lower half: hbuf (ln1 out) then hbuf2 (ln2 out)   [M,256]b each
  //   upper half: aggb (attn out)                        [M,256]b
  unsigned short* hbuf  = (unsigned short*)d_out;
  unsigned short* hbuf2 = (unsigned short*)d_out;
  unsigned short* aggb  = (unsigned short*)((char*)d_out + (size_t)M * 512);
  float* xout = (float*)d_out;

  if (off > ws_size) {
    sentinel_fill<<<2048, 256, 0, stream>>>((float*)d_out, (long)out_size,
                                            (float)ws_size);
    return;
  }

  const int tb = 256;
  const int EB = (E + tb - 1) / tb;
  const int SB = (M + 255) / 256;

  // fused prep: 7 weight jobs + bias concat + deg zero + detect
  prep_weights<<<dim3(1536, 10), 256, 0, stream>>>(
      Wc, Wq, Wk, Wv, Wo, W1, W2, Wct, Wqkvt, Wot, W1t, W2t,
      bq, bk, bv, bqkv, deg, M + 4, (const unsigned int*)ei, E, flag);
  // --- CSR build ---
  conv_hist<<<EB, tb, 0, stream>>>(ei, flag, src32, dst32, deg, E);
  block_sum<<<SB, 256, 0, stream>>>(deg, bsum, M);
  scan_bsum<<<1, 256, 0, stream>>>(bsum, boff, startp + M, SB);
  scan_final<<<SB, 256, 0, stream>>>(deg, boff, startp, cursor, M);
  csr_fill<<<EB, tb, 0, stream>>>(src32, dst32, cursor, csr, E);

  auto gsz = [](int Mz, int Nz) {
    int MT = (Mz + 127) / 128, NT = Nz / 128;
    return 8 * ((MT + 7) / 8) * NT;
  };
  // cs = bf16(silu(c))
  silu_cast<<<(M * 64 + tb - 1) / tb, tb, 0, stream>>>(c, cs, M * 64);
  // modv = cs @ Wc + bc   [M,1536]
  gemm_bf16<0><<<gsz(M, 1536), 256, 0, stream>>>(cs, Wct, bc, nullptr, nullptr,
                                                 modv, M, 1536, 256, 256, 1536);
  // hbuf = modulate(ln(x), shift_msa, scale_msa)
  ln_modulate<<<(M + 3) / 4, 256, 0, stream>>>(x, modv, hbuf, M, 0, 1);
  // qkv = hbuf @ [Wq | kv-interleaved Wk,Wv] + bias   [M,768]
  gemm_bf16<0><<<gsz(M, 768), 256, 0, stream>>>(hbuf, Wqkvt, bqkv, nullptr, nullptr,
                                                qkv, M, 768, 256, 256, 768);
  // aggb(d_out hi) = per-dst softmax gather (no atomics)
  attn_gather<<<(M + 3) / 4, 256, 0, stream>>>(csr, startp, qkv, aggb, M);
  // X1(D) = x + gate_msa * (aggb @ Wo + bo)   [f32]
  gemm_bf16<2><<<gsz(M, 256), 256, 0, stream>>>(aggb, Wot, bo, x, modv + 512,
                                                X1, M, 256, 256, 256, 256);
  // hbuf2(d_out lo) = modulate(ln(X1), shift_mlp, scale_mlp)
  ln_modulate<<<(M + 3) / 4, 256, 0, stream>>>(X1, modv, hbuf2, M, 3, 4);
  // h2(modv cols 0..1024, ld 1536) = gelu(hbuf2 @ W1 + b1)   [M,1024]
  gemm_bf16<1><<<gsz(M, 1024), 256, 0, stream>>>(hbuf2, W1t, b1, nullptr, nullptr,
                                                 modv, M, 1024, 256, 256, 1536);
  // out(d_out) = X1 + gate_mlp * (h2 @ W2 + b2)
  gemm_bf16<2><<<gsz(M, 256), 256, 0, stream>>>(modv, W2t, b2, X1, modv + 1280,
                                                xout, M, 256, 1024, 1536, 256);
}

// Round 9
// 615.740 us; speedup vs baseline: 5.2494x; 1.0202x over previous
//
#include <hip/hip_runtime.h>

// ---------------------------------------------------------------------------
// DiT graph-attention block, MI355X (gfx950).
// R9: epilogue de-VALU-ification — gelu via v*sigmoid(2u) with __expf
//     (libdevice tanhf was ~25 VALU/elem x 64/thread => VALUBusy 53%),
//     repack-LDS XOR swizzle (4 row-quads hit same 8 banks: 1.6M conflicts),
//     __expf in attn_gather + silu_cast.
// ---------------------------------------------------------------------------

typedef __attribute__((ext_vector_type(8))) short bf16x8;
typedef __attribute__((ext_vector_type(8))) unsigned short u16x8;
typedef __attribute__((ext_vector_type(4))) float f32x4;

__device__ __forceinline__ float bf2f(unsigned short u) {
  union { float f; unsigned int i; } x; x.i = ((unsigned int)u) << 16; return x.f;
}
__device__ __forceinline__ unsigned short f2bf(float f) {
  union { float f; unsigned int i; } x; x.f = f;
  unsigned int r = x.i + 0x7fffu + ((x.i >> 16) & 1u);  // RNE
  return (unsigned short)(r >> 16);
}

__device__ __forceinline__ void gload_lds16(const void* g, void* l) {
  __builtin_amdgcn_global_load_lds(
      (const __attribute__((address_space(1))) void*)g,
      (__attribute__((address_space(3))) void*)l, 16, 0, 0);
}

// ---------------------------------------------------------------------------
// Unified bf16 GEMM:  out = epilogue(A[M,K](lda) @ Bt[N,K]^T + bias)
// XCD-grouped 1-D grid (pid%8 = XCD; col-siblings consecutive on one XCD).
// EPI 0: out bf16 = acc+bias               (coalesced LDS-repack stores, ldo)
// EPI 1: out bf16 = gelu_tanh(acc+bias)    (coalesced LDS-repack stores, ldo)
// EPI 2: out f32  = xin + gate*(acc+bias)  (gate bf16 stride 1536, xin ldo)
// ---------------------------------------------------------------------------
template <int EPI>
__global__ __launch_bounds__(256)
void gemm_bf16(const unsigned short* __restrict__ A,
               const unsigned short* __restrict__ Bt,
               const float* __restrict__ bias,
               const float* __restrict__ xin,
               const unsigned short* __restrict__ gate,
               void* __restrict__ out,
               int M, int N, int K, int lda, int ldo) {
  const int NT = N >> 7;
  const int MT = (M + 127) >> 7;
  const int pid = blockIdx.x;
  const int xcd = pid & 7;
  const int j = pid >> 3;
  const int rb = xcd + 8 * (j / NT);
  const int cb = j - (j / NT) * NT;
  if (rb >= MT) return;  // uniform across block

  __shared__ unsigned short At[128 * 64];
  __shared__ unsigned short Bs[128 * 64];
  const int tid = threadIdx.x;
  const int wid = tid >> 6;
  const int lane = tid & 63;
  const int l15 = lane & 15, l4 = lane >> 4;
  const int row0 = rb * 128, col0 = cb * 128;
  const int wr = (wid >> 1) * 64, wc = (wid & 1) * 64;

  f32x4 acc[4][4];
  const f32x4 zf = {0.f, 0.f, 0.f, 0.f};
  for (int m = 0; m < 4; ++m)
    for (int n = 0; n < 4; ++n) acc[m][n] = zf;

  for (int kt = 0; kt < K; kt += 64) {
    __syncthreads();
#pragma unroll
    for (int s = 0; s < 4; ++s) {
      const int p = s * 4096 + tid * 16;           // physical byte in tile
      const int r = p >> 7;                        // tile row
      const int scb = (p & 127) ^ ((r & 7) << 4);  // swizzled source col byte
      int gr = row0 + r; gr = gr < M ? gr : M - 1;
      gload_lds16((const char*)A + ((size_t)gr * lda + kt) * 2 + scb,
                  (char*)At + s * 4096 + wid * 1024);
      const int gc = col0 + r;                     // N multiple of 128
      gload_lds16((const char*)Bt + ((size_t)gc * K + kt) * 2 + scb,
                  (char*)Bs + s * 4096 + wid * 1024);
    }
    __syncthreads();
#pragma unroll
    for (int kk = 0; kk < 64; kk += 32) {
      bf16x8 af[4], bfr[4];
#pragma unroll
      for (int m = 0; m < 4; ++m) {
        const int r = wr + m * 16 + l15;
        const int cb2 = ((kk + l4 * 8) * 2) ^ ((r & 7) << 4);
        af[m] = *(const bf16x8*)((const char*)At + r * 128 + cb2);
      }
#pragma unroll
      for (int n = 0; n < 4; ++n) {
        const int r = wc + n * 16 + l15;
        const int cb2 = ((kk + l4 * 8) * 2) ^ ((r & 7) << 4);
        bfr[n] = *(const bf16x8*)((const char*)Bs + r * 128 + cb2);
      }
#pragma unroll
      for (int m = 0; m < 4; ++m)
#pragma unroll
        for (int n = 0; n < 4; ++n)
          acc[m][n] = __builtin_amdgcn_mfma_f32_16x16x32_bf16(af[m], bfr[n],
                                                              acc[m][n], 0, 0, 0);
    }
  }

  // C/D layout: col=lane&15, row=(lane>>4)*4+reg   [guide §3, m89/m91]
  if (EPI == 2) {
#pragma unroll
    for (int m = 0; m < 4; ++m)
#pragma unroll
      for (int jj = 0; jj < 4; ++jj) {
        const int gr = row0 + wr + m * 16 + l4 * 4 + jj;
        if (gr >= M) continue;
#pragma unroll
        for (int n = 0; n < 4; ++n) {
          const int gc = col0 + wc + n * 16 + l15;
          const float v = acc[m][n][jj] + bias[gc];
          const float gt = bf2f(gate[(size_t)gr * 1536 + gc]);
          ((float*)out)[(size_t)gr * ldo + gc] =
              xin[(size_t)gr * ldo + gc] + gt * v;
        }
      }
  } else {
    // bf16 outputs: repack 64-row halves through At, store bf16x8 coalesced.
    // XOR swizzle (col ^ (row&12)<<2): the 4 l4-quads write rows r+{0,4,8,12}
    // (256B stride -> same banks); swizzle maps them to disjoint 8-bank groups.
    __syncthreads();  // all LDS reads of K-loop done
#pragma unroll
    for (int half = 0; half < 2; ++half) {
      if ((wid >> 1) == half) {
#pragma unroll
        for (int m = 0; m < 4; ++m)
#pragma unroll
          for (int jj = 0; jj < 4; ++jj) {
            const int row_l = m * 16 + l4 * 4 + jj;  // 0..63
            const int swz = (row_l & 12) << 2;       // 0,16,32,48
#pragma unroll
            for (int n = 0; n < 4; ++n) {
              const int col = wc + n * 16 + l15;     // 0..127
              float v = acc[m][n][jj] + bias[col0 + col];
              if (EPI == 1) {
                // gelu_tanh(v) == v * sigmoid(2u), u = 0.79788(v+0.044715v^3)
                const float u2 = 1.5957691216f * (v + 0.044715f * v * v * v);
                v = v / (1.f + __expf(-u2));
              }
              At[row_l * 128 + (col ^ swz)] = f2bf(v);
            }
          }
      }
      __syncthreads();
#pragma unroll
      for (int p = 0; p < 4; ++p) {
        const int u = p * 256 + tid;        // 16B unit id, 1024 total
        const int row_l = u >> 4;           // 64 rows, 16 units each
        const int col8 = ((u & 15) * 8) ^ ((row_l & 12) << 2);
        const int gr = row0 + half * 64 + row_l;
        if (gr < M) {
          const bf16x8 vv = *(const bf16x8*)&At[row_l * 128 + col8];
          *(bf16x8*)((unsigned short*)out + (size_t)gr * ldo + col0 +
                     (((u & 15) * 8))) = vv;
        }
      }
      __syncthreads();
    }
  }
}

// ---------------------------------------------------------------------------
// helpers
// ---------------------------------------------------------------------------
__global__ void sentinel_fill(float* o, long n, float v) {
  long i = (long)blockIdx.x * blockDim.x + threadIdx.x;
  const long st = (long)gridDim.x * blockDim.x;
  for (; i < n; i += st) o[i] = (i == 0) ? v : 0.f;
}

// fused prep: weight transposes (kv-interleave for Wk/Wv), bias concat,
// deg zeroing, and int64-detect.  One launch, grid = dim3(1536, 10).
__global__ void prep_weights(const float* __restrict__ Wc, const float* __restrict__ Wq,
                             const float* __restrict__ Wk, const float* __restrict__ Wv,
                             const float* __restrict__ Wo, const float* __restrict__ W1,
                             const float* __restrict__ W2,
                             unsigned short* __restrict__ Wct,
                             unsigned short* __restrict__ Wqkvt,
                             unsigned short* __restrict__ Wot,
                             unsigned short* __restrict__ W1t,
                             unsigned short* __restrict__ W2t,
                             const float* __restrict__ bq, const float* __restrict__ bk,
                             const float* __restrict__ bv, float* __restrict__ bqkv,
                             int* __restrict__ deg, int Mdeg,
                             const unsigned int* __restrict__ ei_u32, int E,
                             int* __restrict__ flag) {
  const int job = blockIdx.y;
  const int i = blockIdx.x * 256 + threadIdx.x;
  if (job == 7) {  // bias concat (kv-interleaved)
    if (i < 256) bqkv[i] = bq[i];
    else if (i < 512) { int d = i - 256; bqkv[256 + ((d >> 2) << 3) + (d & 3)] = bk[d]; }
    else if (i < 768) { int d = i - 512; bqkv[256 + ((d >> 2) << 3) + 4 + (d & 3)] = bv[d]; }
    return;
  }
  if (job == 8) {  // zero deg
    if (i < Mdeg) deg[i] = 0;
    return;
  }
  if (job == 9) {  // int64 detect (block 0 only)
    if (blockIdx.x != 0) return;
    __shared__ int bad;
    if (threadIdx.x == 0) bad = 0;
    __syncthreads();
    const int n = E < 256 ? E : 256;
    if ((int)threadIdx.x < n && ei_u32[2 * threadIdx.x + 1] != 0u) atomicAdd(&bad, 1);
    __syncthreads();
    if (threadIdx.x == 0) *flag = (bad == 0);
    return;
  }
  const float* W; unsigned short* Wt; int N, kc, mode = 0;
  switch (job) {
    case 0: W = Wc; Wt = Wct; N = 1536; kc = 256; break;
    case 1: W = Wq; Wt = Wqkvt; N = 256; kc = 256; break;
    case 2: W = Wk; Wt = Wqkvt + 256 * 256; N = 256; kc = 256; mode = 1; break;
    case 3: W = Wv; Wt = Wqkvt + 256 * 256; N = 256; kc = 256; mode = 2; break;
    case 4: W = Wo; Wt = Wot; N = 256; kc = 256; break;
    case 5: W = W1; Wt = W1t; N = 1024; kc = 256; break;
    default: W = W2; Wt = W2t; N = 256; kc = 1024; break;
  }
  if (i >= N * kc) return;
  const int kk = i / N, n = i - kk * N;
  int r = n;
  if (mode == 1) r = ((n >> 2) << 3) + (n & 3);
  else if (mode == 2) r = ((n >> 2) << 3) + 4 + (n & 3);
  Wt[(size_t)r * kc + kk] = f2bf(W[(size_t)kk * N + n]);
}

__global__ void silu_cast(const float* __restrict__ c, unsigned short* __restrict__ o,
                          int total4) {
  int i = blockIdx.x * blockDim.x + threadIdx.x;
  if (i >= total4) return;
  float4 v = *(const float4*)&c[(size_t)i * 4];
  ushort4 r;
  r.x = f2bf(v.x / (1.f + __expf(-v.x)));
  r.y = f2bf(v.y / (1.f + __expf(-v.y)));
  r.z = f2bf(v.z / (1.f + __expf(-v.z)));
  r.w = f2bf(v.w / (1.f + __expf(-v.w)));
  *(ushort4*)&o[(size_t)i * 4] = r;
}

// one wave per row: h = ((x-mean)*rstd)*(1+scale)+shift -> bf16
__global__ void ln_modulate(const float* __restrict__ xin,
                            const unsigned short* __restrict__ modv,
                            unsigned short* __restrict__ hout,
                            int M, int cshift, int cscale) {
  const int wid = threadIdx.x >> 6, lane = threadIdx.x & 63;
  const int row = blockIdx.x * 4 + wid;
  if (row >= M) return;
  const float4 x4 = *(const float4*)&xin[(size_t)row * 256 + lane * 4];
  float s = x4.x + x4.y + x4.z + x4.w;
  float ss = x4.x * x4.x + x4.y * x4.y + x4.z * x4.z + x4.w * x4.w;
#pragma unroll
  for (int m = 1; m < 64; m <<= 1) {
    s += __shfl_xor(s, m, 64);
    ss += __shfl_xor(ss, m, 64);
  }
  const float mean = s * (1.f / 256.f);
  const float var = ss * (1.f / 256.f) - mean * mean;
  const float rstd = rsqrtf(var + 1e-6f);
  const ushort4 sh4 = *(const ushort4*)&modv[(size_t)row * 1536 + cshift * 256 + lane * 4];
  const ushort4 sc4 = *(const ushort4*)&modv[(size_t)row * 1536 + cscale * 256 + lane * 4];
  ushort4 o;
  o.x = f2bf((x4.x - mean) * rstd * (1.f + bf2f(sc4.x)) + bf2f(sh4.x));
  o.y = f2bf((x4.y - mean) * rstd * (1.f + bf2f(sc4.y)) + bf2f(sh4.y));
  o.z = f2bf((x4.z - mean) * rstd * (1.f + bf2f(sc4.z)) + bf2f(sh4.z));
  o.w = f2bf((x4.w - mean) * rstd * (1.f + bf2f(sc4.w)) + bf2f(sh4.w));
  *(ushort4*)&hout[(size_t)row * 256 + lane * 4] = o;
}

// unpack edge_index -> src32/dst32 and histogram dst degree (fused)
__global__ void conv_hist(const void* __restrict__ ei, const int* __restrict__ flag,
                          int* __restrict__ src32, int* __restrict__ dst32,
                          int* __restrict__ deg, int E) {
  int e = blockIdx.x * blockDim.x + threadIdx.x;
  if (e >= E) return;
  int s, d;
  if (*flag) {
    const long long* p = (const long long*)ei;
    s = (int)p[e]; d = (int)p[E + e];
  } else {
    const int* p = (const int*)ei;
    s = p[e]; d = p[E + e];
  }
  src32[e] = s; dst32[e] = d;
  atomicAdd(&deg[d], 1);
}

// 3-phase scan
__global__ __launch_bounds__(256)
void block_sum(const int* __restrict__ deg, int* __restrict__ bsum, int M) {
  int i = blockIdx.x * 256 + threadIdx.x;
  int v = (i < M) ? deg[i] : 0;
#pragma unroll
  for (int d = 1; d < 64; d <<= 1) v += __shfl_xor(v, d, 64);
  __shared__ int ws[4];
  const int lane = threadIdx.x & 63, w = threadIdx.x >> 6;
  if (lane == 0) ws[w] = v;
  __syncthreads();
  if (threadIdx.x == 0) bsum[blockIdx.x] = ws[0] + ws[1] + ws[2] + ws[3];
}

__global__ __launch_bounds__(256)
void scan_bsum(const int* __restrict__ bsum, int* __restrict__ boff,
               int* __restrict__ startM, int NB) {
  const int t = threadIdx.x, lane = t & 63, w = t >> 6;
  const int v = (t < NB) ? bsum[t] : 0;
  int s = v;
#pragma unroll
  for (int d = 1; d < 64; d <<= 1) {
    int u = __shfl_up(s, d, 64);
    if (lane >= d) s += u;
  }
  __shared__ int ws[4];
  if (lane == 63) ws[w] = s;
  __syncthreads();
  int add = 0;
  for (int k = 0; k < w; ++k) add += ws[k];
  s += add;
  if (t < NB) boff[t] = s - v;
  if (t == NB - 1) *startM = s;
}

__global__ __launch_bounds__(256)
void scan_final(const int* __restrict__ deg, const int* __restrict__ boff,
                int* __restrict__ start, int* __restrict__ cursor, int M) {
  const int b = blockIdx.x, t = threadIdx.x, i = b * 256 + t;
  const int lane = t & 63, w = t >> 6;
  const int v = (i < M) ? deg[i] : 0;
  int s = v;
#pragma unroll
  for (int d = 1; d < 64; d <<= 1) {
    int u = __shfl_up(s, d, 64);
    if (lane >= d) s += u;
  }
  __shared__ int ws[4];
  if (lane == 63) ws[w] = s;
  __syncthreads();
  int add = boff[b];
  for (int k = 0; k < w; ++k) add += ws[k];
  const int excl = s - v + add;
  if (i < M) { start[i] = excl; cursor[i] = excl; }
}

__global__ void csr_fill(const int* __restrict__ src32, const int* __restrict__ dst32,
                         int* __restrict__ cursor, int* __restrict__ csr, int E) {
  int e = blockIdx.x * blockDim.x + threadIdx.x;
  if (e >= E) return;
  int pos = atomicAdd(&cursor[dst32[e]], 1);
  csr[pos] = src32[e];
}

// one wave per dst node; software-pipelined batch-4 kv gather (up to 8 loads
// in flight per wave).  qkv row: q(256) | kv-interleaved(512).
__global__ __launch_bounds__(256)
void attn_gather(const int* __restrict__ csr, const int* __restrict__ start,
                 const unsigned short* __restrict__ qkv,
                 unsigned short* __restrict__ aggb, int M) {
  const int wid = threadIdx.x >> 6, lane = threadIdx.x & 63;
  const int row = blockIdx.x * 4 + wid;
  if (row >= M) return;
  const ushort4 q4 = *(const ushort4*)&qkv[(size_t)row * 768 + lane * 4];
  const float SC = 0.17677669529663687f;  // 32^-0.5, folded into q
  const float qf0 = bf2f(q4.x) * SC, qf1 = bf2f(q4.y) * SC;
  const float qf2 = bf2f(q4.z) * SC, qf3 = bf2f(q4.w) * SC;
  const int b0 = start[row], e0 = start[row + 1];
  float den = 0.f, a0 = 0.f, a1 = 0.f, a2 = 0.f, a3 = 0.f;

  auto LD = [&](int src) {
    return *(const u16x8*)&qkv[(size_t)src * 768 + 256 + lane * 8];
  };
#define PROC(kvv)                                                            \
  {                                                                          \
    float s = qf0 * bf2f(kvv[0]) + qf1 * bf2f(kvv[1]) +                      \
              qf2 * bf2f(kvv[2]) + qf3 * bf2f(kvv[3]);                       \
    s += __shfl_xor(s, 1, 64);                                               \
    s += __shfl_xor(s, 2, 64);                                               \
    s += __shfl_xor(s, 4, 64);                                               \
    const float ex = __expf(s);                                              \
    den += ex;                                                               \
    a0 += ex * bf2f(kvv[4]); a1 += ex * bf2f(kvv[5]);                        \
    a2 += ex * bf2f(kvv[6]); a3 += ex * bf2f(kvv[7]);                        \
  }

  int i = b0;
  if (i + 4 <= e0) {
    u16x8 kA0 = LD(csr[i]), kA1 = LD(csr[i + 1]);
    u16x8 kA2 = LD(csr[i + 2]), kA3 = LD(csr[i + 3]);
    while (i + 8 <= e0) {
      const u16x8 kB0 = LD(csr[i + 4]), kB1 = LD(csr[i + 5]);
      const u16x8 kB2 = LD(csr[i + 6]), kB3 = LD(csr[i + 7]);
      PROC(kA0); PROC(kA1); PROC(kA2); PROC(kA3);
      kA0 = kB0; kA1 = kB1; kA2 = kB2; kA3 = kB3;
      i += 4;
    }
    PROC(kA0); PROC(kA1); PROC(kA2); PROC(kA3);
    i += 4;
  }
  for (; i < e0; ++i) {
    const u16x8 kv = LD(csr[i]);
    PROC(kv);
  }
#undef PROC

  const float inv = den > 0.f ? 1.f / den : 0.f;
  ushort4 r;
  r.x = f2bf(a0 * inv); r.y = f2bf(a1 * inv);
  r.z = f2bf(a2 * inv); r.w = f2bf(a3 * inv);
  *(ushort4*)&aggb[(size_t)row * 256 + lane * 4] = r;
}

// ---------------------------------------------------------------------------
extern "C" void kernel_launch(void* const* d_in, const int* in_sizes, int n_in,
                              void* d_out, int out_size, void* d_ws, size_t ws_size,
                              hipStream_t stream) {
  (void)n_in;
  const float* x  = (const float*)d_in[0];
  const float* c  = (const float*)d_in[1];
  const void*  ei = d_in[2];
  const float* Wq = (const float*)d_in[3];
  const float* bq = (const float*)d_in[4];
  const float* Wk = (const float*)d_in[5];
  const float* bk = (const float*)d_in[6];
  const float* Wv = (const float*)d_in[7];
  const float* bv = (const float*)d_in[8];
  const float* Wo = (const float*)d_in[9];
  const float* bo = (const float*)d_in[10];
  const float* W1 = (const float*)d_in[11];
  const float* b1 = (const float*)d_in[12];
  const float* W2 = (const float*)d_in[13];
  const float* b2 = (const float*)d_in[14];
  const float* Wc = (const float*)d_in[15];
  const float* bc = (const float*)d_in[16];

  const int M = in_sizes[0] / 256;   // 50000
  const int E = in_sizes[2] / 2;     // 800000

  char* ws = (char*)d_ws;
  size_t off = 0;
  auto carve = [&](size_t bytes) {
    char* p = ws + off;
    off = (off + bytes + 255) & ~(size_t)255;
    return p;
  };
  // persistent: modv [M,1536]b; cols 0..1024 reused as h2 (ldo=1536) after ln2
  unsigned short* modv = (unsigned short*)carve((size_t)M * 1536 * 2);  // 153.6MB
  // region D (M*1536 bytes): cs [M,256]b -> qkv [M,768]b -> X1 [M,256]f32
  char* D = carve((size_t)M * 1536);
  unsigned short* cs  = (unsigned short*)D;
  unsigned short* qkv = (unsigned short*)D;
  float* X1 = (float*)D;
  unsigned short* Wct   = (unsigned short*)carve((size_t)1536 * 256 * 2);
  unsigned short* Wqkvt = (unsigned short*)carve((size_t)768 * 256 * 2);
  unsigned short* Wot   = (unsigned short*)carve((size_t)256 * 256 * 2);
  unsigned short* W1t   = (unsigned short*)carve((size_t)1024 * 256 * 2);
  unsigned short* W2t   = (unsigned short*)carve((size_t)256 * 1024 * 2);
  float* bqkv = (float*)carve(768 * 4);
  int* flag = (int*)carve(256);
  // CSR buffers
  int* src32  = (int*)carve((size_t)E * 4);
  int* dst32  = (int*)carve((size_t)E * 4);
  int* deg    = (int*)carve((size_t)(M + 4) * 4);
  int* startp = (int*)carve((size_t)(M + 4) * 4);
  int* cursor = (int*)carve((size_t)(M + 4) * 4);
  int* csr    = (int*)carve((size_t)E * 4);
  int* bsum   = (int*)carve(1024);
  int* boff   = (int*)carve(1024);

  // d_out (M*256 f32 = M*1024 bytes) aliases:
  //   lower half: hbuf (ln1 out) then hbuf2 (ln2 out)   [M,256]b each
  //   upper half: aggb (attn out)                        [M,256]b
  unsigned short* hbuf  = (unsigned short*)d_out;
  unsigned short* hbuf2 = (unsigned short*)d_out;
  unsigned short* aggb  = (unsigned short*)((char*)d_out + (size_t)M * 512);
  float* xout = (float*)d_out;

  if (off > ws_size) {
    sentinel_fill<<<2048, 256, 0, stream>>>((float*)d_out, (long)out_size,
                                            (float)ws_size);
    return;
  }

  const int tb = 256;
  const int EB = (E + tb - 1) / tb;
  const int SB = (M + 255) / 256;

  // fused prep: 7 weight jobs + bias concat + deg zero + detect
  prep_weights<<<dim3(1536, 10), 256, 0, stream>>>(
      Wc, Wq, Wk, Wv, Wo, W1, W2, Wct, Wqkvt, Wot, W1t, W2t,
      bq, bk, bv, bqkv, deg, M + 4, (const unsigned int*)ei, E, flag);
  // --- CSR build ---
  conv_hist<<<EB, tb, 0, stream>>>(ei, flag, src32, dst32, deg, E);
  block_sum<<<SB, 256, 0, stream>>>(deg, bsum, M);
  scan_bsum<<<1, 256, 0, stream>>>(bsum, boff, startp + M, SB);
  scan_final<<<SB, 256, 0, stream>>>(deg, boff, startp, cursor, M);
  csr_fill<<<EB, tb, 0, stream>>>(src32, dst32, cursor, csr, E);

  auto gsz = [](int Mz, int Nz) {
    int MT = (Mz + 127) / 128, NT = Nz / 128;
    return 8 * ((MT + 7) / 8) * NT;
  };
  // cs = bf16(silu(c))
  silu_cast<<<(M * 64 + tb - 1) / tb, tb, 0, stream>>>(c, cs, M * 64);
  // modv = cs @ Wc + bc   [M,1536]
  gemm_bf16<0><<<gsz(M, 1536), 256, 0, stream>>>(cs, Wct, bc, nullptr, nullptr,
                                                 modv, M, 1536, 256, 256, 1536);
  // hbuf = modulate(ln(x), shift_msa, scale_msa)
  ln_modulate<<<(M + 3) / 4, 256, 0, stream>>>(x, modv, hbuf, M, 0, 1);
  // qkv = hbuf @ [Wq | kv-interleaved Wk,Wv] + bias   [M,768]
  gemm_bf16<0><<<gsz(M, 768), 256, 0, stream>>>(hbuf, Wqkvt, bqkv, nullptr, nullptr,
                                                qkv, M, 768, 256, 256, 768);
  // aggb(d_out hi) = per-dst softmax gather (no atomics)
  attn_gather<<<(M + 3) / 4, 256, 0, stream>>>(csr, startp, qkv, aggb, M);
  // X1(D) = x + gate_msa * (aggb @ Wo + bo)   [f32]
  gemm_bf16<2><<<gsz(M, 256), 256, 0, stream>>>(aggb, Wot, bo, x, modv + 512,
                                                X1, M, 256, 256, 256, 256);
  // hbuf2(d_out lo) = modulate(ln(X1), shift_mlp, scale_mlp)
  ln_modulate<<<(M + 3) / 4, 256, 0, stream>>>(X1, modv, hbuf2, M, 3, 4);
  // h2(modv cols 0..1024, ld 1536) = gelu(hbuf2 @ W1 + b1)   [M,1024]
  gemm_bf16<1><<<gsz(M, 1024), 256, 0, stream>>>(hbuf2, W1t, b1, nullptr, nullptr,
                                                 modv, M, 1024, 256, 256, 1536);
  // out(d_out) = X1 + gate_mlp * (h2 @ W2 + b2)
  gemm_bf16<2><<<gsz(M, 256), 256, 0, stream>>>(modv, W2t, b2, X1, modv + 1280,
                                                xout, M, 256, 1024, 1536, 256);
}